// Round 1
// baseline (794.451 us; speedup 1.0000x reference)
//
#include <hip/hip_runtime.h>

// ---------------------------------------------------------------------------
// GraphSAGE 3-layer encoder, fp32.
//   per layer: h_out = relu?( mean_agg(h)@Wl + b + h@Wr )
// Identity used: segment_sum(h[src])@Wl == segment_sum((h@Wl)[src])
//   -> project first (N*Dout work), scatter small vectors (E*Dout atomics).
// inv_deg[dst] is known before the scatter, so we scatter p[src]*inv_deg[dst]
// directly into r = h@Wr + b (no separate agg buffer, no extra pass).
// ReLU is folded into the NEXT layer's projection load.
// ---------------------------------------------------------------------------

__global__ void fill_zero(float* __restrict__ p, int n) {
    int i = blockIdx.x * blockDim.x + threadIdx.x;
    if (i < n) p[i] = 0.0f;
}

__global__ void deg_count(const int* __restrict__ dst, float* __restrict__ deg, int E) {
    int i = blockIdx.x * blockDim.x + threadIdx.x;
    if (i < E) atomicAdd(&deg[dst[i]], 1.0f);
}

__global__ void deg_inv(float* __restrict__ deg, int n) {
    int i = blockIdx.x * blockDim.x + threadIdx.x;
    if (i < n) {
        float d = deg[i];
        deg[i] = (d > 0.0f) ? (1.0f / d) : 0.0f;
    }
}

// p = x@Wl ; r = x@Wr + b   (optionally relu on the input x)
// Block: NPB node-groups x DOUT dims. Each thread accumulates NPT nodes to
// amortize the LDS weight reads (2 ds_read per 2*NPT FMAs).
template <int DIN, int DOUT, int NPB, int NPT, bool RELU>
__launch_bounds__(NPB * DOUT)
__global__ void proj_kernel(const float* __restrict__ x,
                            const float* __restrict__ Wl,
                            const float* __restrict__ Wr,
                            const float* __restrict__ bl,
                            float* __restrict__ p,
                            float* __restrict__ r,
                            int n) {
    __shared__ float sWl[DIN * DOUT];
    __shared__ float sWr[DIN * DOUT];
    const int T = NPB * DOUT;
    for (int i = threadIdx.x; i < DIN * DOUT; i += T) {
        sWl[i] = Wl[i];
        sWr[i] = Wr[i];
    }
    __syncthreads();

    const int nl = threadIdx.x / DOUT;
    const int j  = threadIdx.x % DOUT;
    const float bj = bl[j];
    const int step = gridDim.x * NPB * NPT;

    for (int node0 = (blockIdx.x * NPB + nl) * NPT; node0 < n; node0 += step) {
        float accp[NPT], accr[NPT];
#pragma unroll
        for (int t = 0; t < NPT; ++t) { accp[t] = 0.0f; accr[t] = 0.0f; }

        if (node0 + NPT <= n) {
#pragma unroll 8
            for (int k4 = 0; k4 < DIN; k4 += 4) {
                float4 xv[NPT];
#pragma unroll
                for (int t = 0; t < NPT; ++t) {
                    float4 v = *reinterpret_cast<const float4*>(
                        x + (size_t)(node0 + t) * DIN + k4);
                    if (RELU) {
                        v.x = fmaxf(v.x, 0.0f); v.y = fmaxf(v.y, 0.0f);
                        v.z = fmaxf(v.z, 0.0f); v.w = fmaxf(v.w, 0.0f);
                    }
                    xv[t] = v;
                }
#pragma unroll
                for (int u = 0; u < 4; ++u) {
                    const float wl = sWl[(k4 + u) * DOUT + j];
                    const float wr = sWr[(k4 + u) * DOUT + j];
#pragma unroll
                    for (int t = 0; t < NPT; ++t) {
                        const float xs = (u == 0) ? xv[t].x
                                       : (u == 1) ? xv[t].y
                                       : (u == 2) ? xv[t].z : xv[t].w;
                        accp[t] = fmaf(xs, wl, accp[t]);
                        accr[t] = fmaf(xs, wr, accr[t]);
                    }
                }
            }
#pragma unroll
            for (int t = 0; t < NPT; ++t) {
                p[(size_t)(node0 + t) * DOUT + j] = accp[t];
                r[(size_t)(node0 + t) * DOUT + j] = accr[t] + bj;
            }
        } else {
            // tail path (not hit for N=200000 with chosen NPB*NPT, kept for safety)
            for (int t = 0; t < NPT; ++t) {
                const int node = node0 + t;
                if (node >= n) break;
                float ap = 0.0f, ar = 0.0f;
                for (int k = 0; k < DIN; ++k) {
                    float xs = x[(size_t)node * DIN + k];
                    if (RELU) xs = fmaxf(xs, 0.0f);
                    ap = fmaf(xs, sWl[k * DOUT + j], ap);
                    ar = fmaf(xs, sWr[k * DOUT + j], ar);
                }
                p[(size_t)node * DOUT + j] = ap;
                r[(size_t)node * DOUT + j] = ar + bj;
            }
        }
    }
}

// out[dst*D + j] += p[src*D + j] * inv_deg[dst]   for every edge, every dim
template <int D>
__global__ void scatter_kernel(const int* __restrict__ src,
                               const int* __restrict__ dst,
                               const float* __restrict__ invdeg,
                               const float* __restrict__ p,
                               float* __restrict__ out,
                               int E) {
    const long long gid = (long long)blockIdx.x * blockDim.x + threadIdx.x;
    const long long total = (long long)E * D;
    if (gid >= total) return;
    const int e = (int)(gid / D);
    const int j = (int)(gid % D);
    const int s = src[e];
    const int d = dst[e];
    const float w = invdeg[d];
    atomicAdd(&out[(size_t)d * D + j], p[(size_t)s * D + j] * w);
}

extern "C" void kernel_launch(void* const* d_in, const int* in_sizes, int n_in,
                              void* d_out, int out_size, void* d_ws, size_t ws_size,
                              hipStream_t stream) {
    const float* x   = (const float*)d_in[0];
    const int*   ei  = (const int*)d_in[1];   // (2, E) int32
    const float* Wl1 = (const float*)d_in[2];
    const float* bl1 = (const float*)d_in[3];
    const float* Wr1 = (const float*)d_in[4];
    const float* Wl2 = (const float*)d_in[5];
    const float* bl2 = (const float*)d_in[6];
    const float* Wr2 = (const float*)d_in[7];
    const float* Wl3 = (const float*)d_in[8];
    const float* bl3 = (const float*)d_in[9];
    const float* Wr3 = (const float*)d_in[10];
    float* out = (float*)d_out;

    const int N = in_sizes[0] / 128;
    const int E = in_sizes[1] / 2;
    const int* src  = ei;
    const int* dstp = ei + E;

    // workspace layout (floats): invdeg[N] | pbuf[N*64] | h1[N*64] | h2[N*32]
    float* ws = (float*)d_ws;
    float* invdeg = ws;
    float* pbuf   = ws + (((size_t)N + 255) / 256) * 256;
    float* h1     = pbuf + (size_t)N * 64;
    float* h2     = h1 + (size_t)N * 64;

    // --- degrees ---
    fill_zero<<<(N + 255) / 256, 256, 0, stream>>>(invdeg, N);
    deg_count<<<(E + 255) / 256, 256, 0, stream>>>(dstp, invdeg, E);
    deg_inv<<<(N + 255) / 256, 256, 0, stream>>>(invdeg, N);

    // --- layer 1: 128 -> 64 ---
    proj_kernel<128, 64, 4, 4, false><<<2048, 256, 0, stream>>>(
        x, Wl1, Wr1, bl1, pbuf, h1, N);
    {
        const long long tot = (long long)E * 64;
        scatter_kernel<64><<<(int)((tot + 255) / 256), 256, 0, stream>>>(
            src, dstp, invdeg, pbuf, h1, E);
    }

    // --- layer 2: 64 -> 32 (relu on input) ---
    proj_kernel<64, 32, 8, 4, true><<<2048, 256, 0, stream>>>(
        h1, Wl2, Wr2, bl2, pbuf, h2, N);
    {
        const long long tot = (long long)E * 32;
        scatter_kernel<32><<<(int)((tot + 255) / 256), 256, 0, stream>>>(
            src, dstp, invdeg, pbuf, h2, E);
    }

    // --- layer 3: 32 -> 20 (relu on input), r written straight into d_out ---
    proj_kernel<32, 20, 16, 4, true><<<2048, 320, 0, stream>>>(
        h2, Wl3, Wr3, bl3, pbuf, out, N);
    {
        const long long tot = (long long)E * 20;
        scatter_kernel<20><<<(int)((tot + 255) / 256), 256, 0, stream>>>(
            src, dstp, invdeg, pbuf, out, E);
    }
}

// Round 2
// 726.441 us; speedup vs baseline: 1.0936x; 1.0936x over previous
//
#include <hip/hip_runtime.h>
#include <hip/hip_bf16.h>
#include <type_traits>

// ---------------------------------------------------------------------------
// GraphSAGE 3-layer encoder, fp32.
//   per layer: h_out = relu?( mean_agg(h)@Wl + b + h@Wr )
// Identity: segment_sum(h[src])@Wl == segment_sum((h@Wl)[src])
//   -> project first, aggregate small vectors.
// R1 -> R2 changes:
//   * atomic scatter replaced by per-call CSR build (hist + scan + fill) and
//     a gather-aggregate kernel (coalesced row loads, non-atomic writes).
//   * layer-1 weights staged in LDS as RNE bf16: LDS 64KB -> 32KB, doubling
//     blocks/CU (occupancy was the proj1 limiter: 21.5% occ, 39.7% VALUBusy).
// ---------------------------------------------------------------------------

// ============================ CSR construction =============================

__global__ void zero_ints(int* __restrict__ p, int n) {
    int i = blockIdx.x * blockDim.x + threadIdx.x;
    if (i < n) p[i] = 0;
}

__global__ void hist_kernel(const int* __restrict__ dst, int* __restrict__ deg, int E) {
    int i = blockIdx.x * blockDim.x + threadIdx.x;
    if (i < E) atomicAdd(&deg[dst[i]], 1);
}

// per-block sums of deg
__global__ void scan_reduce(const int* __restrict__ deg, int* __restrict__ bsum, int n) {
    __shared__ int s[256];
    int i = blockIdx.x * 256 + threadIdx.x;
    s[threadIdx.x] = (i < n) ? deg[i] : 0;
    __syncthreads();
    for (int off = 128; off > 0; off >>= 1) {
        if (threadIdx.x < off) s[threadIdx.x] += s[threadIdx.x + off];
        __syncthreads();
    }
    if (threadIdx.x == 0) bsum[blockIdx.x] = s[0];
}

// single-block exclusive scan of bsum[nb], nb <= 1024
__global__ void scan_top(int* __restrict__ bsum, int nb) {
    __shared__ int s[1024];
    int t = threadIdx.x;
    int v = (t < nb) ? bsum[t] : 0;
    s[t] = v;
    __syncthreads();
    for (int off = 1; off < 1024; off <<= 1) {
        int add = (t >= off) ? s[t - off] : 0;
        __syncthreads();
        s[t] += add;
        __syncthreads();
    }
    if (t < nb) bsum[t] = s[t] - v;  // exclusive
}

// per-block exclusive scan + block offset -> rowptr, cursor
__global__ void scan_final(const int* __restrict__ deg, const int* __restrict__ bsum,
                           int* __restrict__ rowptr, int* __restrict__ cursor,
                           int n, int E) {
    __shared__ int s[256];
    int t = threadIdx.x;
    int i = blockIdx.x * 256 + t;
    int v = (i < n) ? deg[i] : 0;
    s[t] = v;
    __syncthreads();
    for (int off = 1; off < 256; off <<= 1) {
        int add = (t >= off) ? s[t - off] : 0;
        __syncthreads();
        s[t] += add;
        __syncthreads();
    }
    int excl = s[t] - v + bsum[blockIdx.x];
    if (i < n) {
        rowptr[i] = excl;
        cursor[i] = excl;
    }
    if (i == 0) rowptr[n] = E;
}

__global__ void fill_kernel(const int* __restrict__ src, const int* __restrict__ dst,
                            int* __restrict__ cursor, int* __restrict__ csr, int E) {
    int e = blockIdx.x * blockDim.x + threadIdx.x;
    if (e < E) {
        int pos = atomicAdd(&cursor[dst[e]], 1);
        csr[pos] = src[e];
    }
}

// ============================ projection ===================================
// p = x@Wl ; r = x@Wr + b   (optionally relu on input x).
// WB16: stage weights in LDS as RNE-rounded bf16 (halves LDS -> 2x blocks/CU).

template <int DIN, int DOUT, int NPB, int NPT, bool RELU, bool WB16>
__launch_bounds__(NPB * DOUT)
__global__ void proj_kernel(const float* __restrict__ x,
                            const float* __restrict__ Wl,
                            const float* __restrict__ Wr,
                            const float* __restrict__ bl,
                            float* __restrict__ p,
                            float* __restrict__ r,
                            int n) {
    using WT = typename std::conditional<WB16, unsigned short, float>::type;
    __shared__ WT sWl[DIN * DOUT];
    __shared__ WT sWr[DIN * DOUT];
    const int T = NPB * DOUT;
    for (int i = threadIdx.x; i < DIN * DOUT; i += T) {
        if (WB16) {
            __hip_bfloat16 a = __float2bfloat16(Wl[i]);
            __hip_bfloat16 b = __float2bfloat16(Wr[i]);
            sWl[i] = (WT)__bfloat16_as_ushort(a);
            sWr[i] = (WT)__bfloat16_as_ushort(b);
        } else {
            sWl[i] = (WT)Wl[i];
            sWr[i] = (WT)Wr[i];
        }
    }
    __syncthreads();

    const int nl = threadIdx.x / DOUT;
    const int j  = threadIdx.x % DOUT;
    const float bj = bl[j];
    const int step = gridDim.x * NPB * NPT;

    auto ldw = [&](const WT* s, int idx) -> float {
        if (WB16) return __uint_as_float(((unsigned)s[idx]) << 16);
        else return (float)s[idx];
    };

    for (int node0 = (blockIdx.x * NPB + nl) * NPT; node0 < n; node0 += step) {
        float accp[NPT], accr[NPT];
#pragma unroll
        for (int t = 0; t < NPT; ++t) { accp[t] = 0.0f; accr[t] = 0.0f; }

        if (node0 + NPT <= n) {
#pragma unroll 8
            for (int k4 = 0; k4 < DIN; k4 += 4) {
                float4 xv[NPT];
#pragma unroll
                for (int t = 0; t < NPT; ++t) {
                    float4 v = *reinterpret_cast<const float4*>(
                        x + (size_t)(node0 + t) * DIN + k4);
                    if (RELU) {
                        v.x = fmaxf(v.x, 0.0f); v.y = fmaxf(v.y, 0.0f);
                        v.z = fmaxf(v.z, 0.0f); v.w = fmaxf(v.w, 0.0f);
                    }
                    xv[t] = v;
                }
#pragma unroll
                for (int u = 0; u < 4; ++u) {
                    const float wl = ldw(sWl, (k4 + u) * DOUT + j);
                    const float wr = ldw(sWr, (k4 + u) * DOUT + j);
#pragma unroll
                    for (int t = 0; t < NPT; ++t) {
                        const float xs = (u == 0) ? xv[t].x
                                       : (u == 1) ? xv[t].y
                                       : (u == 2) ? xv[t].z : xv[t].w;
                        accp[t] = fmaf(xs, wl, accp[t]);
                        accr[t] = fmaf(xs, wr, accr[t]);
                    }
                }
            }
#pragma unroll
            for (int t = 0; t < NPT; ++t) {
                p[(size_t)(node0 + t) * DOUT + j] = accp[t];
                r[(size_t)(node0 + t) * DOUT + j] = accr[t] + bj;
            }
        } else {
            for (int t = 0; t < NPT; ++t) {
                const int node = node0 + t;
                if (node >= n) break;
                float ap = 0.0f, ar = 0.0f;
                for (int k = 0; k < DIN; ++k) {
                    float xs = x[(size_t)node * DIN + k];
                    if (RELU) xs = fmaxf(xs, 0.0f);
                    ap = fmaf(xs, ldw(sWl, k * DOUT + j), ap);
                    ar = fmaf(xs, ldw(sWr, k * DOUT + j), ar);
                }
                p[(size_t)node * DOUT + j] = ap;
                r[(size_t)node * DOUT + j] = ar + bj;
            }
        }
    }
}

// ============================ aggregation ==================================
// out[d*D + l] += (1/deg) * sum_{i in row(d)} p[csr[i]*D + l]
// L lanes cooperate per dst node (L = pow2 >= D); coalesced row loads.

template <int D, int L>
__global__ void agg_kernel(const int* __restrict__ rowptr,
                           const int* __restrict__ csr,
                           const float* __restrict__ p,
                           float* __restrict__ out,
                           int n) {
    long long gid = (long long)blockIdx.x * blockDim.x + threadIdx.x;
    int d = (int)(gid / L);
    int l = (int)(gid % L);
    if (d >= n || l >= D) return;
    int beg = rowptr[d], end = rowptr[d + 1];
    int deg = end - beg;
    if (deg <= 0) return;
    float sum = 0.0f;
    for (int i = beg; i < end; ++i) {
        int s = csr[i];
        sum += p[(size_t)s * D + l];
    }
    out[(size_t)d * D + l] += sum * (1.0f / (float)deg);
}

// ============================ launcher =====================================

extern "C" void kernel_launch(void* const* d_in, const int* in_sizes, int n_in,
                              void* d_out, int out_size, void* d_ws, size_t ws_size,
                              hipStream_t stream) {
    const float* x   = (const float*)d_in[0];
    const int*   ei  = (const int*)d_in[1];   // (2, E) int32
    const float* Wl1 = (const float*)d_in[2];
    const float* bl1 = (const float*)d_in[3];
    const float* Wr1 = (const float*)d_in[4];
    const float* Wl2 = (const float*)d_in[5];
    const float* bl2 = (const float*)d_in[6];
    const float* Wr2 = (const float*)d_in[7];
    const float* Wl3 = (const float*)d_in[8];
    const float* bl3 = (const float*)d_in[9];
    const float* Wr3 = (const float*)d_in[10];
    float* out = (float*)d_out;

    const int N = in_sizes[0] / 128;
    const int E = in_sizes[1] / 2;
    const int* src  = ei;
    const int* dstp = ei + E;

    // workspace: A = pbuf (N*64 f) | B = h1 (N*64 f) | C = h2 (N*32 f)
    //            rowptr (N+1 i) | csr (E i)
    // transient CSR-build ints (degi, cursor, bsum) alias A (dead before proj1).
    float* ws = (float*)d_ws;
    float* A = ws;
    float* B = A + (size_t)N * 64;
    float* C = B + (size_t)N * 64;
    int* rowptr = (int*)(C + (size_t)N * 32);
    int* csr    = rowptr + (N + 1);

    int* degi   = (int*)A;
    int* cursor = degi + N;
    int* bsum   = cursor + N;

    const int NB = (N + 255) / 256;  // 782 <= 1024, required by scan_top

    // --- CSR build ---
    zero_ints<<<NB, 256, 0, stream>>>(degi, N);
    hist_kernel<<<(E + 255) / 256, 256, 0, stream>>>(dstp, degi, E);
    scan_reduce<<<NB, 256, 0, stream>>>(degi, bsum, N);
    scan_top<<<1, 1024, 0, stream>>>(bsum, NB);
    scan_final<<<NB, 256, 0, stream>>>(degi, bsum, rowptr, cursor, N, E);
    fill_kernel<<<(E + 255) / 256, 256, 0, stream>>>(src, dstp, cursor, csr, E);

    // --- layer 1: 128 -> 64 (bf16 weights in LDS: 32KB -> 4 blocks/CU) ---
    proj_kernel<128, 64, 4, 4, false, true><<<2048, 256, 0, stream>>>(
        x, Wl1, Wr1, bl1, A, B, N);
    agg_kernel<64, 64><<<(int)(((long long)N * 64 + 255) / 256), 256, 0, stream>>>(
        rowptr, csr, A, B, N);

    // --- layer 2: 64 -> 32 (relu on input) ---
    proj_kernel<64, 32, 8, 4, true, false><<<2048, 256, 0, stream>>>(
        B, Wl2, Wr2, bl2, A, C, N);
    agg_kernel<32, 32><<<(int)(((long long)N * 32 + 255) / 256), 256, 0, stream>>>(
        rowptr, csr, A, C, N);

    // --- layer 3: 32 -> 20 (relu on input), r written straight into d_out ---
    proj_kernel<32, 20, 16, 4, true, false><<<2048, 320, 0, stream>>>(
        C, Wl3, Wr3, bl3, A, out, N);
    agg_kernel<20, 32><<<(int)(((long long)N * 32 + 255) / 256), 256, 0, stream>>>(
        rowptr, csr, A, out, N);
}

// Round 3
// 497.713 us; speedup vs baseline: 1.5962x; 1.4596x over previous
//
#include <hip/hip_runtime.h>
#include <hip/hip_bf16.h>

// ---------------------------------------------------------------------------
// GraphSAGE 3-layer encoder, fp32 in/out.
//   per layer: h_out = relu?( mean_agg(h)@Wl + b + h@Wr )
// Identity: segment_sum(h[src])@Wl == segment_sum((h@Wl)[src])
//   -> project first, aggregate small vectors via CSR gather.
// R2 -> R3: projections rewritten on MFMA (v_mfma_f32_16x16x32_bf16).
//   R2's fp32 proj was issue-rate bound (broadcast VMEM + scalar ds_read_u16
//   + fp32 FMA issue; VALUBusy 43%, occupancy-insensitive). MFMA cuts FMA
//   issues 64x and removes all in-loop LDS reads (B fragments preloaded to
//   registers, one ds_read_b128 each).
// ---------------------------------------------------------------------------

typedef __attribute__((ext_vector_type(8))) short short8;
typedef __attribute__((ext_vector_type(4))) float f32x4;

// ============================ CSR construction =============================

__global__ void zero_ints(int* __restrict__ p, int n) {
    int i = blockIdx.x * blockDim.x + threadIdx.x;
    if (i < n) p[i] = 0;
}

__global__ void hist_kernel(const int* __restrict__ dst, int* __restrict__ deg, int E) {
    int i = blockIdx.x * blockDim.x + threadIdx.x;
    if (i < E) atomicAdd(&deg[dst[i]], 1);
}

__global__ void scan_reduce(const int* __restrict__ deg, int* __restrict__ bsum, int n) {
    __shared__ int s[256];
    int i = blockIdx.x * 256 + threadIdx.x;
    s[threadIdx.x] = (i < n) ? deg[i] : 0;
    __syncthreads();
    for (int off = 128; off > 0; off >>= 1) {
        if (threadIdx.x < off) s[threadIdx.x] += s[threadIdx.x + off];
        __syncthreads();
    }
    if (threadIdx.x == 0) bsum[blockIdx.x] = s[0];
}

__global__ void scan_top(int* __restrict__ bsum, int nb) {
    __shared__ int s[1024];
    int t = threadIdx.x;
    int v = (t < nb) ? bsum[t] : 0;
    s[t] = v;
    __syncthreads();
    for (int off = 1; off < 1024; off <<= 1) {
        int add = (t >= off) ? s[t - off] : 0;
        __syncthreads();
        s[t] += add;
        __syncthreads();
    }
    if (t < nb) bsum[t] = s[t] - v;  // exclusive
}

__global__ void scan_final(const int* __restrict__ deg, const int* __restrict__ bsum,
                           int* __restrict__ rowptr, int* __restrict__ cursor,
                           int n, int E) {
    __shared__ int s[256];
    int t = threadIdx.x;
    int i = blockIdx.x * 256 + t;
    int v = (i < n) ? deg[i] : 0;
    s[t] = v;
    __syncthreads();
    for (int off = 1; off < 256; off <<= 1) {
        int add = (t >= off) ? s[t - off] : 0;
        __syncthreads();
        s[t] += add;
        __syncthreads();
    }
    int excl = s[t] - v + bsum[blockIdx.x];
    if (i < n) {
        rowptr[i] = excl;
        cursor[i] = excl;
    }
    if (i == 0) rowptr[n] = E;
}

__global__ void fill_kernel(const int* __restrict__ src, const int* __restrict__ dst,
                            int* __restrict__ cursor, int* __restrict__ csr, int E) {
    int e = blockIdx.x * blockDim.x + threadIdx.x;
    if (e < E) {
        int pos = atomicAdd(&cursor[dst[e]], 1);
        csr[pos] = src[e];
    }
}

// ============================ MFMA projection ==============================
// Computes p = x@Wl and r = x@Wr + b in one pass. Weight cols concatenated:
// cols [0,DP) -> p, [DP,DP+DR) -> r, [DP+DR,DT2) zero-padded.
// Wt staged transposed in LDS (bf16): Wt[c][k], so a B fragment (fixed col,
// 8 consecutive k) is one 16B LDS read. B frags live in registers for the
// whole node loop.
// Block = 4 waves. CH column-chunks x NG=4/CH node-groups per block-iter.
// MFMA 16x16x32: A[m=lane&15][k=(lane>>4)*8+i]; B[k=(lane>>4)*8+i][n=lane&15];
// D col=lane&15, row=(lane>>4)*4+reg  (m89/m120-verified layouts).
// Assumes full 16-node groups (N % (NG*16) == 0 for our launches).

template <int DIN, int DP, int DR, int DT2, int CH, bool RELU>
__launch_bounds__(256)
__global__ void proj_mfma(const float* __restrict__ x,
                          const float* __restrict__ Wl,
                          const float* __restrict__ Wr,
                          const float* __restrict__ bl,
                          float* __restrict__ p,
                          float* __restrict__ r,
                          int n) {
    constexpr int NG = 4 / CH;           // node groups per block-iter
    constexpr int TILES = DT2 / 16;
    constexpr int TW = TILES / CH;       // col tiles per wave
    constexpr int S = DIN / 32;          // k-steps
    constexpr int WS = DIN + 8;          // LDS row stride (ushorts), pad

    __shared__ unsigned short sW[DT2 * WS];

    const int tid = threadIdx.x;
    // stage [Wl|Wr] transposed as bf16
    for (int i = tid; i < DT2 * DIN; i += 256) {
        const int c = i / DIN, k = i % DIN;
        float v = 0.0f;
        if (c < DP) v = Wl[k * DP + c];
        else if (c < DP + DR) v = Wr[k * DR + (c - DP)];
        sW[c * WS + k] = __bfloat16_as_ushort(__float2bfloat16(v));
    }
    __syncthreads();

    const int wave = tid >> 6, lane = tid & 63;
    const int ng = wave % NG;            // which node group
    const int ch = wave / NG;            // which column chunk
    const int q = lane >> 4, ln = lane & 15;

    // preload B fragments (one ds_read_b128 each), fixed for all nodes
    short8 bf[TW][S];
#pragma unroll
    for (int t = 0; t < TW; ++t) {
        const int c = ch * (TW * 16) + t * 16 + ln;
#pragma unroll
        for (int s = 0; s < S; ++s) {
            bf[t][s] = *reinterpret_cast<const short8*>(&sW[c * WS + s * 32 + q * 8]);
        }
    }
    // per-tile epilogue info (fixed per lane)
    int colg[TW];
    float bias[TW];
#pragma unroll
    for (int t = 0; t < TW; ++t) {
        colg[t] = ch * (TW * 16) + t * 16 + ln;
        bias[t] = (colg[t] >= DP && colg[t] < DP + DR) ? bl[colg[t] - DP] : 0.0f;
    }

    const int npi = NG * 16;             // nodes per block-iter
    for (int nb = blockIdx.x * npi + ng * 16; nb < n; nb += gridDim.x * npi) {
        // load A fragments: 16 nodes x DIN, fp32 -> bf16 (RNE)
        short8 af[S];
        const float* xr = x + (size_t)(nb + ln) * DIN + q * 8;
#pragma unroll
        for (int s = 0; s < S; ++s) {
            float4 v0 = *reinterpret_cast<const float4*>(xr + s * 32);
            float4 v1 = *reinterpret_cast<const float4*>(xr + s * 32 + 4);
            if (RELU) {
                v0.x = fmaxf(v0.x, 0.0f); v0.y = fmaxf(v0.y, 0.0f);
                v0.z = fmaxf(v0.z, 0.0f); v0.w = fmaxf(v0.w, 0.0f);
                v1.x = fmaxf(v1.x, 0.0f); v1.y = fmaxf(v1.y, 0.0f);
                v1.z = fmaxf(v1.z, 0.0f); v1.w = fmaxf(v1.w, 0.0f);
            }
            short8 a;
            a[0] = (short)__bfloat16_as_ushort(__float2bfloat16(v0.x));
            a[1] = (short)__bfloat16_as_ushort(__float2bfloat16(v0.y));
            a[2] = (short)__bfloat16_as_ushort(__float2bfloat16(v0.z));
            a[3] = (short)__bfloat16_as_ushort(__float2bfloat16(v0.w));
            a[4] = (short)__bfloat16_as_ushort(__float2bfloat16(v1.x));
            a[5] = (short)__bfloat16_as_ushort(__float2bfloat16(v1.y));
            a[6] = (short)__bfloat16_as_ushort(__float2bfloat16(v1.z));
            a[7] = (short)__bfloat16_as_ushort(__float2bfloat16(v1.w));
            af[s] = a;
        }

        f32x4 acc[TW];
#pragma unroll
        for (int t = 0; t < TW; ++t) acc[t] = (f32x4){0.f, 0.f, 0.f, 0.f};
#pragma unroll
        for (int s = 0; s < S; ++s)
#pragma unroll
            for (int t = 0; t < TW; ++t)
                acc[t] = __builtin_amdgcn_mfma_f32_16x16x32_bf16(af[s], bf[t][s], acc[t], 0, 0, 0);

        // epilogue: rows nb + q*4 + rr, col colg[t]
#pragma unroll
        for (int t = 0; t < TW; ++t) {
            const int c = colg[t];
#pragma unroll
            for (int rr = 0; rr < 4; ++rr) {
                const int row = nb + q * 4 + rr;
                if (c < DP) {
                    p[(size_t)row * DP + c] = acc[t][rr];
                } else if (c < DP + DR) {
                    r[(size_t)row * DR + (c - DP)] = acc[t][rr] + bias[t];
                }
            }
        }
    }
}

// ============================ aggregation ==================================
// out[d*D + l] += (1/deg) * sum_{i in row(d)} p[csr[i]*D + l]

template <int D, int L>
__global__ void agg_kernel(const int* __restrict__ rowptr,
                           const int* __restrict__ csr,
                           const float* __restrict__ p,
                           float* __restrict__ out,
                           int n) {
    long long gid = (long long)blockIdx.x * blockDim.x + threadIdx.x;
    int d = (int)(gid / L);
    int l = (int)(gid % L);
    if (d >= n || l >= D) return;
    int beg = rowptr[d], end = rowptr[d + 1];
    int deg = end - beg;
    if (deg <= 0) return;
    float sum = 0.0f;
    for (int i = beg; i < end; ++i) {
        int s = csr[i];
        sum += p[(size_t)s * D + l];
    }
    out[(size_t)d * D + l] += sum * (1.0f / (float)deg);
}

// ============================ launcher =====================================

extern "C" void kernel_launch(void* const* d_in, const int* in_sizes, int n_in,
                              void* d_out, int out_size, void* d_ws, size_t ws_size,
                              hipStream_t stream) {
    const float* x   = (const float*)d_in[0];
    const int*   ei  = (const int*)d_in[1];   // (2, E) int32
    const float* Wl1 = (const float*)d_in[2];
    const float* bl1 = (const float*)d_in[3];
    const float* Wr1 = (const float*)d_in[4];
    const float* Wl2 = (const float*)d_in[5];
    const float* bl2 = (const float*)d_in[6];
    const float* Wr2 = (const float*)d_in[7];
    const float* Wl3 = (const float*)d_in[8];
    const float* bl3 = (const float*)d_in[9];
    const float* Wr3 = (const float*)d_in[10];
    float* out = (float*)d_out;

    const int N = in_sizes[0] / 128;
    const int E = in_sizes[1] / 2;
    const int* src  = ei;
    const int* dstp = ei + E;

    // workspace: A = pbuf (N*64 f) | B = h1 (N*64 f) | C = h2 (N*32 f)
    //            rowptr (N+1 i) | csr (E i)
    // transient CSR-build ints alias A (dead before proj1 writes A).
    float* ws = (float*)d_ws;
    float* A = ws;
    float* B = A + (size_t)N * 64;
    float* C = B + (size_t)N * 64;
    int* rowptr = (int*)(C + (size_t)N * 32);
    int* csr    = rowptr + (N + 1);

    int* degi   = (int*)A;
    int* cursor = degi + N;
    int* bsum   = cursor + N;

    const int NB = (N + 255) / 256;  // 782 <= 1024 (scan_top limit)

    // --- CSR build ---
    zero_ints<<<NB, 256, 0, stream>>>(degi, N);
    hist_kernel<<<(E + 255) / 256, 256, 0, stream>>>(dstp, degi, E);
    scan_reduce<<<NB, 256, 0, stream>>>(degi, bsum, N);
    scan_top<<<1, 1024, 0, stream>>>(bsum, NB);
    scan_final<<<NB, 256, 0, stream>>>(degi, bsum, rowptr, cursor, N, E);
    fill_kernel<<<(E + 255) / 256, 256, 0, stream>>>(src, dstp, cursor, csr, E);

    // --- layer 1: 128 -> 64 ---  DT2=128, CH=2 (2 node-groups x 2 col-halves)
    proj_mfma<128, 64, 64, 128, 2, false><<<512, 256, 0, stream>>>(
        x, Wl1, Wr1, bl1, A, B, N);
    agg_kernel<64, 64><<<(int)(((long long)N * 64 + 255) / 256), 256, 0, stream>>>(
        rowptr, csr, A, B, N);

    // --- layer 2: 64 -> 32 (relu on input) ---  DT2=64, CH=1
    proj_mfma<64, 32, 32, 64, 1, true><<<384, 256, 0, stream>>>(
        B, Wl2, Wr2, bl2, A, C, N);
    agg_kernel<32, 32><<<(int)(((long long)N * 32 + 255) / 256), 256, 0, stream>>>(
        rowptr, csr, A, C, N);

    // --- layer 3: 32 -> 20 (relu on input), r straight into d_out ---
    // DT2=48 (40 used, 8 zero-pad cols), CH=1
    proj_mfma<32, 20, 20, 48, 1, true><<<384, 256, 0, stream>>>(
        C, Wl3, Wr3, bl3, A, out, N);
    agg_kernel<20, 32><<<(int)(((long long)N * 32 + 255) / 256), 256, 0, stream>>>(
        rowptr, csr, A, out, N);
}

// Round 4
// 435.486 us; speedup vs baseline: 1.8243x; 1.1429x over previous
//
#include <hip/hip_runtime.h>
#include <hip/hip_bf16.h>

// ---------------------------------------------------------------------------
// GraphSAGE 3-layer encoder, fp32 in/out.
//   per layer: h_out = relu?( mean_agg(h)@Wl + b + h@Wr )
// Identity: segment_sum(h[src])@Wl == segment_sum((h@Wl)[src])
//   -> project first (MFMA bf16), aggregate small vectors via CSR gather.
// R3 -> R4:
//   * proj grids were the occupancy cap (512 blocks = 2/CU; all pipes idle).
//     LDS pad dropped (exactly 32KB -> 5 blocks/CU), grid 1280/1563.
//   * agg: float4 row loads (L=D/4 lanes/node, 4x fewer instrs) + unroll-4
//     degree loop (4 independent csr->p chains) to break the serial
//     dependent-load chain.
// ---------------------------------------------------------------------------

typedef __attribute__((ext_vector_type(8))) short short8;
typedef __attribute__((ext_vector_type(4))) float f32x4;

// ============================ CSR construction =============================

__global__ void zero_ints(int* __restrict__ p, int n) {
    int i = blockIdx.x * blockDim.x + threadIdx.x;
    if (i < n) p[i] = 0;
}

__global__ void hist_kernel(const int* __restrict__ dst, int* __restrict__ deg, int E) {
    int i = blockIdx.x * blockDim.x + threadIdx.x;
    if (i < E) atomicAdd(&deg[dst[i]], 1);
}

__global__ void scan_reduce(const int* __restrict__ deg, int* __restrict__ bsum, int n) {
    __shared__ int s[256];
    int i = blockIdx.x * 256 + threadIdx.x;
    s[threadIdx.x] = (i < n) ? deg[i] : 0;
    __syncthreads();
    for (int off = 128; off > 0; off >>= 1) {
        if (threadIdx.x < off) s[threadIdx.x] += s[threadIdx.x + off];
        __syncthreads();
    }
    if (threadIdx.x == 0) bsum[blockIdx.x] = s[0];
}

__global__ void scan_top(int* __restrict__ bsum, int nb) {
    __shared__ int s[1024];
    int t = threadIdx.x;
    int v = (t < nb) ? bsum[t] : 0;
    s[t] = v;
    __syncthreads();
    for (int off = 1; off < 1024; off <<= 1) {
        int add = (t >= off) ? s[t - off] : 0;
        __syncthreads();
        s[t] += add;
        __syncthreads();
    }
    if (t < nb) bsum[t] = s[t] - v;  // exclusive
}

__global__ void scan_final(const int* __restrict__ deg, const int* __restrict__ bsum,
                           int* __restrict__ rowptr, int* __restrict__ cursor,
                           int n, int E) {
    __shared__ int s[256];
    int t = threadIdx.x;
    int i = blockIdx.x * 256 + t;
    int v = (i < n) ? deg[i] : 0;
    s[t] = v;
    __syncthreads();
    for (int off = 1; off < 256; off <<= 1) {
        int add = (t >= off) ? s[t - off] : 0;
        __syncthreads();
        s[t] += add;
        __syncthreads();
    }
    int excl = s[t] - v + bsum[blockIdx.x];
    if (i < n) {
        rowptr[i] = excl;
        cursor[i] = excl;
    }
    if (i == 0) rowptr[n] = E;
}

__global__ void fill_kernel(const int* __restrict__ src, const int* __restrict__ dst,
                            int* __restrict__ cursor, int* __restrict__ csr, int E) {
    int e = blockIdx.x * blockDim.x + threadIdx.x;
    if (e < E) {
        int pos = atomicAdd(&cursor[dst[e]], 1);
        csr[pos] = src[e];
    }
}

// ============================ MFMA projection ==============================
// p = x@Wl ; r = x@Wr + b in one pass. Weight cols concatenated:
// [0,DP)->p, [DP,DP+DR)->r, rest zero-pad. Wt transposed in LDS (bf16);
// B fragments preloaded to registers (one ds_read_b128 each, once/block).
// MFMA 16x16x32: A[m=lane&15][k=(lane>>4)*8+i]; D col=lane&15,
// row=(lane>>4)*4+reg (m89/m120-verified).

template <int DIN, int DP, int DR, int DT2, int CH, bool RELU>
__launch_bounds__(256)
__global__ void proj_mfma(const float* __restrict__ x,
                          const float* __restrict__ Wl,
                          const float* __restrict__ Wr,
                          const float* __restrict__ bl,
                          float* __restrict__ p,
                          float* __restrict__ r,
                          int n) {
    constexpr int NG = 4 / CH;
    constexpr int TILES = DT2 / 16;
    constexpr int TW = TILES / CH;
    constexpr int S = DIN / 32;
    constexpr int WS = DIN;              // no pad: keeps LDS at pow2 (5 blk/CU for L1)

    __shared__ unsigned short sW[DT2 * WS];

    const int tid = threadIdx.x;
    for (int i = tid; i < DT2 * DIN; i += 256) {
        const int c = i / DIN, k = i % DIN;
        float v = 0.0f;
        if (c < DP) v = Wl[k * DP + c];
        else if (c < DP + DR) v = Wr[k * DR + (c - DP)];
        sW[c * WS + k] = __bfloat16_as_ushort(__float2bfloat16(v));
    }
    __syncthreads();

    const int wave = tid >> 6, lane = tid & 63;
    const int ng = wave % NG;
    const int ch = wave / NG;
    const int q = lane >> 4, ln = lane & 15;

    short8 bf[TW][S];
#pragma unroll
    for (int t = 0; t < TW; ++t) {
        const int c = ch * (TW * 16) + t * 16 + ln;
#pragma unroll
        for (int s = 0; s < S; ++s) {
            bf[t][s] = *reinterpret_cast<const short8*>(&sW[c * WS + s * 32 + q * 8]);
        }
    }
    int colg[TW];
    float bias[TW];
#pragma unroll
    for (int t = 0; t < TW; ++t) {
        colg[t] = ch * (TW * 16) + t * 16 + ln;
        bias[t] = (colg[t] >= DP && colg[t] < DP + DR) ? bl[colg[t] - DP] : 0.0f;
    }

    const int npi = NG * 16;
    for (int nb = blockIdx.x * npi + ng * 16; nb < n; nb += gridDim.x * npi) {
        short8 af[S];
        const float* xr = x + (size_t)(nb + ln) * DIN + q * 8;
#pragma unroll
        for (int s = 0; s < S; ++s) {
            float4 v0 = *reinterpret_cast<const float4*>(xr + s * 32);
            float4 v1 = *reinterpret_cast<const float4*>(xr + s * 32 + 4);
            if (RELU) {
                v0.x = fmaxf(v0.x, 0.0f); v0.y = fmaxf(v0.y, 0.0f);
                v0.z = fmaxf(v0.z, 0.0f); v0.w = fmaxf(v0.w, 0.0f);
                v1.x = fmaxf(v1.x, 0.0f); v1.y = fmaxf(v1.y, 0.0f);
                v1.z = fmaxf(v1.z, 0.0f); v1.w = fmaxf(v1.w, 0.0f);
            }
            short8 a;
            a[0] = (short)__bfloat16_as_ushort(__float2bfloat16(v0.x));
            a[1] = (short)__bfloat16_as_ushort(__float2bfloat16(v0.y));
            a[2] = (short)__bfloat16_as_ushort(__float2bfloat16(v0.z));
            a[3] = (short)__bfloat16_as_ushort(__float2bfloat16(v0.w));
            a[4] = (short)__bfloat16_as_ushort(__float2bfloat16(v1.x));
            a[5] = (short)__bfloat16_as_ushort(__float2bfloat16(v1.y));
            a[6] = (short)__bfloat16_as_ushort(__float2bfloat16(v1.z));
            a[7] = (short)__bfloat16_as_ushort(__float2bfloat16(v1.w));
            af[s] = a;
        }

        f32x4 acc[TW];
#pragma unroll
        for (int t = 0; t < TW; ++t) acc[t] = (f32x4){0.f, 0.f, 0.f, 0.f};
#pragma unroll
        for (int s = 0; s < S; ++s)
#pragma unroll
            for (int t = 0; t < TW; ++t)
                acc[t] = __builtin_amdgcn_mfma_f32_16x16x32_bf16(af[s], bf[t][s], acc[t], 0, 0, 0);

#pragma unroll
        for (int t = 0; t < TW; ++t) {
            const int c = colg[t];
#pragma unroll
            for (int rr = 0; rr < 4; ++rr) {
                const int row = nb + q * 4 + rr;
                if (c < DP) {
                    p[(size_t)row * DP + c] = acc[t][rr];
                } else if (c < DP + DR) {
                    r[(size_t)row * DR + (c - DP)] = acc[t][rr] + bias[t];
                }
            }
        }
    }
}

// ============================ aggregation ==================================
// out[d] += mean of p rows listed in csr[rowptr[d]..rowptr[d+1]).
// L lanes per node, float4 per lane (L*4 >= D; lanes >= D/4 idle).
// Degree loop unrolled 4x: four independent csr->row load chains in flight.

template <int D, int L>
__global__ void agg_kernel(const int* __restrict__ rowptr,
                           const int* __restrict__ csr,
                           const float* __restrict__ p,
                           float* __restrict__ out,
                           int n) {
    constexpr int RQ = D / 4;            // float4s per row
    long long gid = (long long)blockIdx.x * blockDim.x + threadIdx.x;
    int d = (int)(gid / L);
    int l = (int)(gid % L);
    if (d >= n || l >= RQ) return;
    int beg = rowptr[d], end = rowptr[d + 1];
    int deg = end - beg;
    if (deg <= 0) return;

    const float4* pr = reinterpret_cast<const float4*>(p);
    float sx = 0.f, sy = 0.f, sz = 0.f, sw = 0.f;
    int i = beg;
    for (; i + 4 <= end; i += 4) {
        int s0 = csr[i], s1 = csr[i + 1], s2 = csr[i + 2], s3 = csr[i + 3];
        float4 a = pr[(size_t)s0 * RQ + l];
        float4 b = pr[(size_t)s1 * RQ + l];
        float4 c = pr[(size_t)s2 * RQ + l];
        float4 e = pr[(size_t)s3 * RQ + l];
        sx += (a.x + b.x) + (c.x + e.x);
        sy += (a.y + b.y) + (c.y + e.y);
        sz += (a.z + b.z) + (c.z + e.z);
        sw += (a.w + b.w) + (c.w + e.w);
    }
    for (; i < end; ++i) {
        int s = csr[i];
        float4 a = pr[(size_t)s * RQ + l];
        sx += a.x; sy += a.y; sz += a.z; sw += a.w;
    }
    const float inv = 1.0f / (float)deg;
    float4* o = reinterpret_cast<float4*>(out) + (size_t)d * RQ + l;
    float4 cur = *o;
    cur.x += sx * inv; cur.y += sy * inv;
    cur.z += sz * inv; cur.w += sw * inv;
    *o = cur;
}

// ============================ launcher =====================================

extern "C" void kernel_launch(void* const* d_in, const int* in_sizes, int n_in,
                              void* d_out, int out_size, void* d_ws, size_t ws_size,
                              hipStream_t stream) {
    const float* x   = (const float*)d_in[0];
    const int*   ei  = (const int*)d_in[1];   // (2, E) int32
    const float* Wl1 = (const float*)d_in[2];
    const float* bl1 = (const float*)d_in[3];
    const float* Wr1 = (const float*)d_in[4];
    const float* Wl2 = (const float*)d_in[5];
    const float* bl2 = (const float*)d_in[6];
    const float* Wr2 = (const float*)d_in[7];
    const float* Wl3 = (const float*)d_in[8];
    const float* bl3 = (const float*)d_in[9];
    const float* Wr3 = (const float*)d_in[10];
    float* out = (float*)d_out;

    const int N = in_sizes[0] / 128;
    const int E = in_sizes[1] / 2;
    const int* src  = ei;
    const int* dstp = ei + E;

    // workspace: A = pbuf (N*64 f) | B = h1 (N*64 f) | C = h2 (N*32 f)
    //            rowptr (N+1 i) | csr (E i)
    // transient CSR-build ints alias A (dead before proj1 writes A).
    float* ws = (float*)d_ws;
    float* A = ws;
    float* B = A + (size_t)N * 64;
    float* C = B + (size_t)N * 64;
    int* rowptr = (int*)(C + (size_t)N * 32);
    int* csr    = rowptr + (N + 1);

    int* degi   = (int*)A;
    int* cursor = degi + N;
    int* bsum   = cursor + N;

    const int NB = (N + 255) / 256;  // 782 <= 1024 (scan_top limit)

    // --- CSR build ---
    zero_ints<<<NB, 256, 0, stream>>>(degi, N);
    hist_kernel<<<(E + 255) / 256, 256, 0, stream>>>(dstp, degi, E);
    scan_reduce<<<NB, 256, 0, stream>>>(degi, bsum, N);
    scan_top<<<1, 1024, 0, stream>>>(bsum, NB);
    scan_final<<<NB, 256, 0, stream>>>(degi, bsum, rowptr, cursor, N, E);
    fill_kernel<<<(E + 255) / 256, 256, 0, stream>>>(src, dstp, cursor, csr, E);

    // --- layer 1: 128 -> 64 ---  DT2=128, CH=2; LDS 32KB -> 5 blocks/CU
    proj_mfma<128, 64, 64, 128, 2, false><<<1280, 256, 0, stream>>>(
        x, Wl1, Wr1, bl1, A, B, N);
    agg_kernel<64, 16><<<(int)(((long long)N * 16 + 255) / 256), 256, 0, stream>>>(
        rowptr, csr, A, B, N);

    // --- layer 2: 64 -> 32 (relu on input) ---  DT2=64, CH=1
    proj_mfma<64, 32, 32, 64, 1, true><<<1563, 256, 0, stream>>>(
        B, Wl2, Wr2, bl2, A, C, N);
    agg_kernel<32, 8><<<(int)(((long long)N * 8 + 255) / 256), 256, 0, stream>>>(
        rowptr, csr, A, C, N);

    // --- layer 3: 32 -> 20 (relu on input), r straight into d_out ---
    // DT2=48 (40 used, 8 zero-pad cols), CH=1
    proj_mfma<32, 20, 20, 48, 1, true><<<1563, 256, 0, stream>>>(
        C, Wl3, Wr3, bl3, A, out, N);
    agg_kernel<20, 8><<<(int)(((long long)N * 8 + 255) / 256), 256, 0, stream>>>(
        rowptr, csr, A, out, N);
}

// Round 5
// 396.712 us; speedup vs baseline: 2.0026x; 1.0977x over previous
//
#include <hip/hip_runtime.h>
#include <hip/hip_bf16.h>

// ---------------------------------------------------------------------------
// GraphSAGE 3-layer encoder, fp32 in/out.
//   per layer: h_out = relu?( mean_agg(h)@Wl + b + h@Wr )
// Identity: segment_sum(h[src])@Wl == segment_sum((h@Wl)[src])
//   -> project first (MFMA bf16), aggregate small vectors via CSR gather.
// R4 -> R5:
//   * proj was latency-bound (1.3 TB/s, per-iter vmcnt drain). Now software-
//     pipelined: double-buffered raw x in registers, loads for iter i+1 issued
//     before compute of iter i; cvt/relu deferred to compute phase.
//   * LDS pad restored (WS=DIN+8): R4's unpadded stride-256B made B-frag
//     ds_read_b128 16-way bank-conflicted (2.29M conflict cycles).
//   * intermediates p1,h1,p2,h2 stored bf16: halves traffic; proj2/3 A-frags
//     are direct short8 loads. p3/out stay fp32.
// ---------------------------------------------------------------------------

typedef __attribute__((ext_vector_type(8))) short short8;
typedef __attribute__((ext_vector_type(4))) float f32x4;

__device__ inline unsigned short f2b(float x) {
    return __bfloat16_as_ushort(__float2bfloat16(x));
}
__device__ inline float b2f(unsigned short u) {
    return __uint_as_float(((unsigned)u) << 16);
}

// ============================ CSR construction =============================

__global__ void zero_ints(int* __restrict__ p, int n) {
    int i = blockIdx.x * blockDim.x + threadIdx.x;
    if (i < n) p[i] = 0;
}

__global__ void hist_kernel(const int* __restrict__ dst, int* __restrict__ deg, int E) {
    int i = blockIdx.x * blockDim.x + threadIdx.x;
    if (i < E) atomicAdd(&deg[dst[i]], 1);
}

__global__ void scan_reduce(const int* __restrict__ deg, int* __restrict__ bsum, int n) {
    __shared__ int s[256];
    int i = blockIdx.x * 256 + threadIdx.x;
    s[threadIdx.x] = (i < n) ? deg[i] : 0;
    __syncthreads();
    for (int off = 128; off > 0; off >>= 1) {
        if (threadIdx.x < off) s[threadIdx.x] += s[threadIdx.x + off];
        __syncthreads();
    }
    if (threadIdx.x == 0) bsum[blockIdx.x] = s[0];
}

__global__ void scan_top(int* __restrict__ bsum, int nb) {
    __shared__ int s[1024];
    int t = threadIdx.x;
    int v = (t < nb) ? bsum[t] : 0;
    s[t] = v;
    __syncthreads();
    for (int off = 1; off < 1024; off <<= 1) {
        int add = (t >= off) ? s[t - off] : 0;
        __syncthreads();
        s[t] += add;
        __syncthreads();
    }
    if (t < nb) bsum[t] = s[t] - v;  // exclusive
}

__global__ void scan_final(const int* __restrict__ deg, const int* __restrict__ bsum,
                           int* __restrict__ rowptr, int* __restrict__ cursor,
                           int n, int E) {
    __shared__ int s[256];
    int t = threadIdx.x;
    int i = blockIdx.x * 256 + t;
    int v = (i < n) ? deg[i] : 0;
    s[t] = v;
    __syncthreads();
    for (int off = 1; off < 256; off <<= 1) {
        int add = (t >= off) ? s[t - off] : 0;
        __syncthreads();
        s[t] += add;
        __syncthreads();
    }
    int excl = s[t] - v + bsum[blockIdx.x];
    if (i < n) {
        rowptr[i] = excl;
        cursor[i] = excl;
    }
    if (i == 0) rowptr[n] = E;
}

__global__ void fill_kernel(const int* __restrict__ src, const int* __restrict__ dst,
                            int* __restrict__ cursor, int* __restrict__ csr, int E) {
    int e = blockIdx.x * blockDim.x + threadIdx.x;
    if (e < E) {
        int pos = atomicAdd(&cursor[dst[e]], 1);
        csr[pos] = src[e];
    }
}

// ============================ MFMA projection ==============================
// p = x@Wl ; r = x@Wr + b in one pass. Weight cols concatenated:
// [0,DP)->p, [DP,DP+DR)->r, rest zero-pad. W^T staged in LDS (bf16, padded
// row stride); B fragments preloaded to registers once per block.
// MFMA 16x16x32: A[m=lane&15][k=(lane>>4)*8+i]; D col=lane&15,
// row=(lane>>4)*4+reg (verified by R3/R4 passing).
// Software pipeline: raw x for iter i+1 loaded into alternate register
// buffer before compute of iter i (cvt/relu deferred to compute phase).

template <int DIN, int DP, int DR, int DT2, int CH, int NU,
          bool RELU, bool IN_BF16, bool OUT_BF16>
__launch_bounds__(256)
__global__ void proj_mfma(const void* __restrict__ xv,
                          const float* __restrict__ Wl,
                          const float* __restrict__ Wr,
                          const float* __restrict__ bl,
                          void* __restrict__ pv,
                          void* __restrict__ rv,
                          int n) {
    constexpr int NG = 4 / CH;           // wave node-slots per block
    constexpr int TILES = DT2 / 16;
    constexpr int TW = TILES / CH;       // col tiles per wave
    constexpr int S = DIN / 32;          // MFMA k-steps
    constexpr int WS = DIN + 8;          // padded LDS row stride (ushorts)

    __shared__ unsigned short sW[DT2 * WS];

    const int tid = threadIdx.x;
    for (int i = tid; i < DT2 * DIN; i += 256) {
        const int c = i / DIN, k = i % DIN;
        float v = 0.0f;
        if (c < DP) v = Wl[k * DP + c];
        else if (c < DP + DR) v = Wr[k * DR + (c - DP)];
        sW[c * WS + k] = f2b(v);
    }
    __syncthreads();

    const int wave = tid >> 6, lane = tid & 63;
    const int ng = wave % NG;
    const int ch = wave / NG;
    const int q = lane >> 4, ln = lane & 15;

    // B fragments: one ds_read_b128 each, once per block
    short8 bf[TW][S];
#pragma unroll
    for (int t = 0; t < TW; ++t) {
        const int c = ch * (TW * 16) + t * 16 + ln;
#pragma unroll
        for (int s = 0; s < S; ++s)
            bf[t][s] = *reinterpret_cast<const short8*>(&sW[c * WS + s * 32 + q * 8]);
    }
    int colg[TW];
    float bias[TW];
#pragma unroll
    for (int t = 0; t < TW; ++t) {
        colg[t] = ch * (TW * 16) + t * 16 + ln;
        bias[t] = (colg[t] >= DP && colg[t] < DP + DR) ? bl[colg[t] - DP] : 0.0f;
    }

    // raw-data double buffers (unused pair is dead code, DCE'd)
    float4 rf0[NU][2 * S], rf1[NU][2 * S];
    short8 rb0[NU][S], rb1[NU][S];

    auto load_groups = [&](float4 (&rf)[NU][2 * S], short8 (&rb)[NU][S], int nbase) {
#pragma unroll
        for (int g = 0; g < NU; ++g) {
            const int base = nbase + (ng * NU + g) * 16;
            if (base >= n) continue;  // wave-uniform
            if constexpr (IN_BF16) {
                const unsigned short* xr =
                    (const unsigned short*)xv + (size_t)(base + ln) * DIN + q * 8;
#pragma unroll
                for (int s = 0; s < S; ++s)
                    rb[g][s] = *reinterpret_cast<const short8*>(xr + s * 32);
            } else {
                const float* xr = (const float*)xv + (size_t)(base + ln) * DIN + q * 8;
#pragma unroll
                for (int s = 0; s < S; ++s) {
                    rf[g][2 * s]     = *reinterpret_cast<const float4*>(xr + s * 32);
                    rf[g][2 * s + 1] = *reinterpret_cast<const float4*>(xr + s * 32 + 4);
                }
            }
        }
    };

    auto compute_groups = [&](float4 (&rf)[NU][2 * S], short8 (&rb)[NU][S], int nbase) {
#pragma unroll
        for (int g = 0; g < NU; ++g) {
            const int base = nbase + (ng * NU + g) * 16;
            if (base >= n) continue;
            short8 af[S];
#pragma unroll
            for (int s = 0; s < S; ++s) {
                if constexpr (IN_BF16) {
                    short8 a = rb[g][s];
                    if (RELU) {
#pragma unroll
                        for (int j = 0; j < 8; ++j)
                            a[j] = ((short)a[j] < 0) ? (short)0 : a[j];
                    }
                    af[s] = a;
                } else {
                    float4 v0 = rf[g][2 * s], v1 = rf[g][2 * s + 1];
                    if (RELU) {
                        v0.x = fmaxf(v0.x, 0.0f); v0.y = fmaxf(v0.y, 0.0f);
                        v0.z = fmaxf(v0.z, 0.0f); v0.w = fmaxf(v0.w, 0.0f);
                        v1.x = fmaxf(v1.x, 0.0f); v1.y = fmaxf(v1.y, 0.0f);
                        v1.z = fmaxf(v1.z, 0.0f); v1.w = fmaxf(v1.w, 0.0f);
                    }
                    short8 a;
                    a[0] = (short)f2b(v0.x); a[1] = (short)f2b(v0.y);
                    a[2] = (short)f2b(v0.z); a[3] = (short)f2b(v0.w);
                    a[4] = (short)f2b(v1.x); a[5] = (short)f2b(v1.y);
                    a[6] = (short)f2b(v1.z); a[7] = (short)f2b(v1.w);
                    af[s] = a;
                }
            }

            f32x4 acc[TW];
#pragma unroll
            for (int t = 0; t < TW; ++t) acc[t] = (f32x4){0.f, 0.f, 0.f, 0.f};
#pragma unroll
            for (int s = 0; s < S; ++s)
#pragma unroll
                for (int t = 0; t < TW; ++t)
                    acc[t] = __builtin_amdgcn_mfma_f32_16x16x32_bf16(
                        af[s], bf[t][s], acc[t], 0, 0, 0);

#pragma unroll
            for (int t = 0; t < TW; ++t) {
                const int c = colg[t];
#pragma unroll
                for (int rr = 0; rr < 4; ++rr) {
                    const int row = base + q * 4 + rr;
                    if (c < DP) {
                        if constexpr (OUT_BF16)
                            ((unsigned short*)pv)[(size_t)row * DP + c] = f2b(acc[t][rr]);
                        else
                            ((float*)pv)[(size_t)row * DP + c] = acc[t][rr];
                    } else if (c < DP + DR) {
                        const float v = acc[t][rr] + bias[t];
                        if constexpr (OUT_BF16)
                            ((unsigned short*)rv)[(size_t)row * DR + (c - DP)] = f2b(v);
                        else
                            ((float*)rv)[(size_t)row * DR + (c - DP)] = v;
                    }
                }
            }
        }
    };

    const int npi = NG * NU * 16;        // nodes per block-iteration
    const int stride = gridDim.x * npi;
    int nb = blockIdx.x * npi;
    if (nb >= n) return;
    load_groups(rf0, rb0, nb);
    while (true) {
        const int nb1 = nb + stride;
        if (nb1 < n) load_groups(rf1, rb1, nb1);
        compute_groups(rf0, rb0, nb);
        nb = nb1;
        if (nb >= n) break;
        const int nb2 = nb + stride;
        if (nb2 < n) load_groups(rf0, rb0, nb2);
        compute_groups(rf1, rb1, nb);
        nb = nb2;
        if (nb >= n) break;
    }
}

// ============================ aggregation ==================================
// out[d] += mean over csr row of p rows. bf16 buffers: L=D/8 lanes per node,
// one short8 (16B) per lane per gathered row; fp32 accumulation; unroll-4
// keeps 4 independent csr->row chains in flight.

template <int D, int L>
__global__ void agg_bf16(const int* __restrict__ rowptr,
                         const int* __restrict__ csr,
                         const unsigned short* __restrict__ p,
                         unsigned short* __restrict__ out,
                         int n) {
    constexpr int RQ = D / 8;            // short8s per row
    long long gid = (long long)blockIdx.x * blockDim.x + threadIdx.x;
    int d = (int)(gid / L);
    int l = (int)(gid % L);
    if (d >= n) return;
    int beg = rowptr[d], end = rowptr[d + 1];
    int deg = end - beg;
    if (deg <= 0) return;

    const short8* pr = reinterpret_cast<const short8*>(p);
    float s[8];
#pragma unroll
    for (int j = 0; j < 8; ++j) s[j] = 0.0f;

    int i = beg;
    for (; i + 4 <= end; i += 4) {
        int e0 = csr[i], e1 = csr[i + 1], e2 = csr[i + 2], e3 = csr[i + 3];
        short8 a = pr[(size_t)e0 * RQ + l];
        short8 b = pr[(size_t)e1 * RQ + l];
        short8 c = pr[(size_t)e2 * RQ + l];
        short8 e = pr[(size_t)e3 * RQ + l];
#pragma unroll
        for (int j = 0; j < 8; ++j)
            s[j] += (b2f((unsigned short)a[j]) + b2f((unsigned short)b[j])) +
                    (b2f((unsigned short)c[j]) + b2f((unsigned short)e[j]));
    }
    for (; i < end; ++i) {
        short8 a = pr[(size_t)csr[i] * RQ + l];
#pragma unroll
        for (int j = 0; j < 8; ++j) s[j] += b2f((unsigned short)a[j]);
    }

    const float inv = 1.0f / (float)deg;
    short8* o = reinterpret_cast<short8*>(out) + (size_t)d * RQ + l;
    short8 cur = *o;
#pragma unroll
    for (int j = 0; j < 8; ++j) {
        float v = b2f((unsigned short)cur[j]) + s[j] * inv;
        cur[j] = (short)f2b(v);
    }
    *o = cur;
}

// fp32 variant for the final layer (out = d_out, fp32; D may not be /8)
template <int D, int L>
__global__ void agg_f32(const int* __restrict__ rowptr,
                        const int* __restrict__ csr,
                        const float* __restrict__ p,
                        float* __restrict__ out,
                        int n) {
    constexpr int RQ = D / 4;            // float4s per row
    long long gid = (long long)blockIdx.x * blockDim.x + threadIdx.x;
    int d = (int)(gid / L);
    int l = (int)(gid % L);
    if (d >= n || l >= RQ) return;
    int beg = rowptr[d], end = rowptr[d + 1];
    int deg = end - beg;
    if (deg <= 0) return;

    const float4* pr = reinterpret_cast<const float4*>(p);
    float sx = 0.f, sy = 0.f, sz = 0.f, sw = 0.f;
    int i = beg;
    for (; i + 4 <= end; i += 4) {
        int s0 = csr[i], s1 = csr[i + 1], s2 = csr[i + 2], s3 = csr[i + 3];
        float4 a = pr[(size_t)s0 * RQ + l];
        float4 b = pr[(size_t)s1 * RQ + l];
        float4 c = pr[(size_t)s2 * RQ + l];
        float4 e = pr[(size_t)s3 * RQ + l];
        sx += (a.x + b.x) + (c.x + e.x);
        sy += (a.y + b.y) + (c.y + e.y);
        sz += (a.z + b.z) + (c.z + e.z);
        sw += (a.w + b.w) + (c.w + e.w);
    }
    for (; i < end; ++i) {
        float4 a = pr[(size_t)csr[i] * RQ + l];
        sx += a.x; sy += a.y; sz += a.z; sw += a.w;
    }
    const float inv = 1.0f / (float)deg;
    float4* o = reinterpret_cast<float4*>(out) + (size_t)d * RQ + l;
    float4 cur = *o;
    cur.x += sx * inv; cur.y += sy * inv;
    cur.z += sz * inv; cur.w += sw * inv;
    *o = cur;
}

// ============================ launcher =====================================

extern "C" void kernel_launch(void* const* d_in, const int* in_sizes, int n_in,
                              void* d_out, int out_size, void* d_ws, size_t ws_size,
                              hipStream_t stream) {
    const float* x   = (const float*)d_in[0];
    const int*   ei  = (const int*)d_in[1];   // (2, E) int32
    const float* Wl1 = (const float*)d_in[2];
    const float* bl1 = (const float*)d_in[3];
    const float* Wr1 = (const float*)d_in[4];
    const float* Wl2 = (const float*)d_in[5];
    const float* bl2 = (const float*)d_in[6];
    const float* Wr2 = (const float*)d_in[7];
    const float* Wl3 = (const float*)d_in[8];
    const float* bl3 = (const float*)d_in[9];
    const float* Wr3 = (const float*)d_in[10];
    float* out = (float*)d_out;

    const int N = in_sizes[0] / 128;
    const int E = in_sizes[1] / 2;
    const int* src  = ei;
    const int* dstp = ei + E;

    // workspace (bf16 intermediates):
    //   A1 bf16 N*64 | B bf16 N*64 | A2 bf16 N*32 | C bf16 N*32 |
    //   A3 f32 N*20 | rowptr (N+1) | csr (E)
    // transient CSR ints (degi, cursor, bsum) alias A3 (dead before proj3).
    unsigned short* A1 = (unsigned short*)d_ws;
    unsigned short* Bb = A1 + (size_t)N * 64;
    unsigned short* A2 = Bb + (size_t)N * 64;
    unsigned short* Cb = A2 + (size_t)N * 32;
    float* A3 = (float*)(Cb + (size_t)N * 32);
    int* rowptr = (int*)(A3 + (size_t)N * 20);
    int* csr    = rowptr + (N + 1);

    int* degi   = (int*)A3;
    int* cursor = degi + N;
    int* bsum   = cursor + N;

    const int NB = (N + 255) / 256;  // 782 <= 1024 (scan_top limit)

    // --- CSR build ---
    zero_ints<<<NB, 256, 0, stream>>>(degi, N);
    hist_kernel<<<(E + 255) / 256, 256, 0, stream>>>(dstp, degi, E);
    scan_reduce<<<NB, 256, 0, stream>>>(degi, bsum, N);
    scan_top<<<1, 1024, 0, stream>>>(bsum, NB);
    scan_final<<<NB, 256, 0, stream>>>(degi, bsum, rowptr, cursor, N, E);
    fill_kernel<<<(E + 255) / 256, 256, 0, stream>>>(src, dstp, cursor, csr, E);

    // --- layer 1: 128 -> 64 --- fp32 in, bf16 out; CH=2, NU=1, npi=32
    // grid 1250: exactly 5 iterations per block (200000/32/1250)
    proj_mfma<128, 64, 64, 128, 2, 1, false, false, true><<<1250, 256, 0, stream>>>(
        x, Wl1, Wr1, bl1, A1, Bb, N);
    agg_bf16<64, 8><<<(int)(((long long)N * 8 + 255) / 256), 256, 0, stream>>>(
        rowptr, csr, A1, Bb, N);

    // --- layer 2: 64 -> 32 --- bf16 in (relu), bf16 out; CH=1, NU=2, npi=128
    proj_mfma<64, 32, 32, 64, 1, 2, true, true, true><<<782, 256, 0, stream>>>(
        Bb, Wl2, Wr2, bl2, A2, Cb, N);
    agg_bf16<32, 4><<<(int)(((long long)N * 4 + 255) / 256), 256, 0, stream>>>(
        rowptr, csr, A2, Cb, N);

    // --- layer 3: 32 -> 20 --- bf16 in (relu), fp32 out (p3=A3, r -> d_out)
    proj_mfma<32, 20, 20, 48, 1, 2, true, true, false><<<782, 256, 0, stream>>>(
        Cb, Wl3, Wr3, bl3, A3, out, N);
    agg_f32<20, 8><<<(int)(((long long)N * 8 + 255) / 256), 256, 0, stream>>>(
        rowptr, csr, A3, out, N);
}

// Round 6
// 360.334 us; speedup vs baseline: 2.2048x; 1.1010x over previous
//
#include <hip/hip_runtime.h>
#include <hip/hip_bf16.h>

// ---------------------------------------------------------------------------
// GraphSAGE 3-layer encoder, fp32 in/out.
//   per layer: h_out = relu?( mean_agg(h)@Wl + b + h@Wr )
// Identity: segment_sum(h[src])@Wl == segment_sum((h@Wl)[src])
//   -> project first (MFMA bf16), aggregate small vectors via CSR gather.
// R5 -> R6:
//   * R5's reg-resident B-frags + x double-buffer needed ~160 VGPRs; compiler
//     spilled ~50 to scratch inside the loop (VGPR_Count=96, occ 16%, 10k
//     cyc/iter). B-frags now re-read from LDS each iteration (ds_read_b128,
//     +8-pad keeps them at the 8-phase b128 floor); only the raw-x double
//     buffer lives in registers. __launch_bounds__(256,4) pins VGPR<=128.
//   * weight staging vectorized: float4 loads along the col dim (16
//     independent loads/thread vs 64 serial scalar loads).
//   * proj1 grid = 1024 (exactly 4 blocks/CU resident, balanced).
// ---------------------------------------------------------------------------

typedef __attribute__((ext_vector_type(8))) short short8;
typedef __attribute__((ext_vector_type(4))) float f32x4;

__device__ inline unsigned short f2b(float x) {
    return __bfloat16_as_ushort(__float2bfloat16(x));
}
__device__ inline float b2f(unsigned short u) {
    return __uint_as_float(((unsigned)u) << 16);
}

// ============================ CSR construction =============================

__global__ void zero_ints(int* __restrict__ p, int n) {
    int i = blockIdx.x * blockDim.x + threadIdx.x;
    if (i < n) p[i] = 0;
}

__global__ void hist_kernel(const int* __restrict__ dst, int* __restrict__ deg, int E) {
    int i = blockIdx.x * blockDim.x + threadIdx.x;
    if (i < E) atomicAdd(&deg[dst[i]], 1);
}

__global__ void scan_reduce(const int* __restrict__ deg, int* __restrict__ bsum, int n) {
    __shared__ int s[256];
    int i = blockIdx.x * 256 + threadIdx.x;
    s[threadIdx.x] = (i < n) ? deg[i] : 0;
    __syncthreads();
    for (int off = 128; off > 0; off >>= 1) {
        if (threadIdx.x < off) s[threadIdx.x] += s[threadIdx.x + off];
        __syncthreads();
    }
    if (threadIdx.x == 0) bsum[blockIdx.x] = s[0];
}

__global__ void scan_top(int* __restrict__ bsum, int nb) {
    __shared__ int s[1024];
    int t = threadIdx.x;
    int v = (t < nb) ? bsum[t] : 0;
    s[t] = v;
    __syncthreads();
    for (int off = 1; off < 1024; off <<= 1) {
        int add = (t >= off) ? s[t - off] : 0;
        __syncthreads();
        s[t] += add;
        __syncthreads();
    }
    if (t < nb) bsum[t] = s[t] - v;  // exclusive
}

__global__ void scan_final(const int* __restrict__ deg, const int* __restrict__ bsum,
                           int* __restrict__ rowptr, int* __restrict__ cursor,
                           int n, int E) {
    __shared__ int s[256];
    int t = threadIdx.x;
    int i = blockIdx.x * 256 + t;
    int v = (i < n) ? deg[i] : 0;
    s[t] = v;
    __syncthreads();
    for (int off = 1; off < 256; off <<= 1) {
        int add = (t >= off) ? s[t - off] : 0;
        __syncthreads();
        s[t] += add;
        __syncthreads();
    }
    int excl = s[t] - v + bsum[blockIdx.x];
    if (i < n) {
        rowptr[i] = excl;
        cursor[i] = excl;
    }
    if (i == 0) rowptr[n] = E;
}

__global__ void fill_kernel(const int* __restrict__ src, const int* __restrict__ dst,
                            int* __restrict__ cursor, int* __restrict__ csr, int E) {
    int e = blockIdx.x * blockDim.x + threadIdx.x;
    if (e < E) {
        int pos = atomicAdd(&cursor[dst[e]], 1);
        csr[pos] = src[e];
    }
}

// ============================ MFMA projection ==============================
// p = x@Wl ; r = x@Wr + b in one pass. Weight cols concatenated:
// [0,DP)->p, [DP,DP+DR)->r, rest zero-pad. W^T staged in LDS bf16 with +8
// ushort row pad; B fragments read per-iteration (ds_read_b128, at the b128
// 8-phase floor). Raw x double-buffered in registers across grid-stride
// iterations; cvt/relu deferred to compute phase.
// MFMA 16x16x32: A[m=lane&15][k=(lane>>4)*8+i]; D col=lane&15,
// row=(lane>>4)*4+reg (verified by R3-R5 passing).

template <int DIN, int DP, int DR, int DT2, int CH, int NU,
          bool RELU, bool IN_BF16, bool OUT_BF16>
__launch_bounds__(256, 4)
__global__ void proj_mfma(const void* __restrict__ xv,
                          const float* __restrict__ Wl,
                          const float* __restrict__ Wr,
                          const float* __restrict__ bl,
                          void* __restrict__ pv,
                          void* __restrict__ rv,
                          int n) {
    constexpr int NG = 4 / CH;           // wave node-slots per block
    constexpr int TILES = DT2 / 16;
    constexpr int TW = TILES / CH;       // col tiles per wave
    constexpr int S = DIN / 32;          // MFMA k-steps
    constexpr int WS = DIN + 8;          // padded LDS row stride (ushorts)
    constexpr int C4 = DT2 / 4;

    __shared__ unsigned short sW[DT2 * WS];

    const int tid = threadIdx.x;
    // vectorized staging: float4 along cols, transpose into LDS
    for (int idx = tid; idx < DIN * C4; idx += 256) {
        const int k = idx / C4, c = (idx % C4) * 4;
        float4 v = {0.f, 0.f, 0.f, 0.f};
        if (c < DP)            v = *reinterpret_cast<const float4*>(Wl + k * DP + c);
        else if (c < DP + DR)  v = *reinterpret_cast<const float4*>(Wr + k * DR + (c - DP));
        sW[(c + 0) * WS + k] = f2b(v.x);
        sW[(c + 1) * WS + k] = f2b(v.y);
        sW[(c + 2) * WS + k] = f2b(v.z);
        sW[(c + 3) * WS + k] = f2b(v.w);
    }
    __syncthreads();

    const int wave = tid >> 6, lane = tid & 63;
    const int ng = wave % NG;
    const int ch = wave / NG;
    const int q = lane >> 4, ln = lane & 15;
    const int colbase = ch * (TW * 16);

    // per-lane LDS base for B-frag reads (col = colbase + t*16 + ln)
    const unsigned short* lbase = &sW[(colbase + ln) * WS + q * 8];

    int colg[TW];
    float bias[TW];
#pragma unroll
    for (int t = 0; t < TW; ++t) {
        colg[t] = colbase + t * 16 + ln;
        bias[t] = (colg[t] >= DP && colg[t] < DP + DR) ? bl[colg[t] - DP] : 0.0f;
    }

    // raw-x double buffers (unused dtype pair is DCE'd)
    float4 rf0[NU][2 * S], rf1[NU][2 * S];
    short8 rb0[NU][S], rb1[NU][S];

    auto load_groups = [&](float4 (&rf)[NU][2 * S], short8 (&rb)[NU][S], int nbase) {
#pragma unroll
        for (int g = 0; g < NU; ++g) {
            const int base = nbase + (ng * NU + g) * 16;
            if (base >= n) continue;  // wave-uniform
            if constexpr (IN_BF16) {
                const unsigned short* xr =
                    (const unsigned short*)xv + (size_t)(base + ln) * DIN + q * 8;
#pragma unroll
                for (int s = 0; s < S; ++s)
                    rb[g][s] = *reinterpret_cast<const short8*>(xr + s * 32);
            } else {
                const float* xr = (const float*)xv + (size_t)(base + ln) * DIN + q * 8;
#pragma unroll
                for (int s = 0; s < S; ++s) {
                    rf[g][2 * s]     = *reinterpret_cast<const float4*>(xr + s * 32);
                    rf[g][2 * s + 1] = *reinterpret_cast<const float4*>(xr + s * 32 + 4);
                }
            }
        }
    };

    auto compute_groups = [&](float4 (&rf)[NU][2 * S], short8 (&rb)[NU][S], int nbase) {
#pragma unroll
        for (int g = 0; g < NU; ++g) {
            const int base = nbase + (ng * NU + g) * 16;
            if (base >= n) continue;
            short8 af[S];
#pragma unroll
            for (int s = 0; s < S; ++s) {
                if constexpr (IN_BF16) {
                    short8 a = rb[g][s];
                    if (RELU) {
#pragma unroll
                        for (int j = 0; j < 8; ++j)
                            a[j] = ((short)a[j] < 0) ? (short)0 : a[j];
                    }
                    af[s] = a;
                } else {
                    float4 v0 = rf[g][2 * s], v1 = rf[g][2 * s + 1];
                    if (RELU) {
                        v0.x = fmaxf(v0.x, 0.0f); v0.y = fmaxf(v0.y, 0.0f);
                        v0.z = fmaxf(v0.z, 0.0f); v0.w = fmaxf(v0.w, 0.0f);
                        v1.x = fmaxf(v1.x, 0.0f); v1.y = fmaxf(v1.y, 0.0f);
                        v1.z = fmaxf(v1.z, 0.0f); v1.w = fmaxf(v1.w, 0.0f);
                    }
                    short8 a;
                    a[0] = (short)f2b(v0.x); a[1] = (short)f2b(v0.y);
                    a[2] = (short)f2b(v0.z); a[3] = (short)f2b(v0.w);
                    a[4] = (short)f2b(v1.x); a[5] = (short)f2b(v1.y);
                    a[6] = (short)f2b(v1.z); a[7] = (short)f2b(v1.w);
                    af[s] = a;
                }
            }

            f32x4 acc[TW];
#pragma unroll
            for (int t = 0; t < TW; ++t) acc[t] = (f32x4){0.f, 0.f, 0.f, 0.f};
#pragma unroll
            for (int s = 0; s < S; ++s)
#pragma unroll
                for (int t = 0; t < TW; ++t) {
                    short8 bf = *reinterpret_cast<const short8*>(
                        lbase + (size_t)t * 16 * WS + s * 32);
                    acc[t] = __builtin_amdgcn_mfma_f32_16x16x32_bf16(
                        af[s], bf, acc[t], 0, 0, 0);
                }

#pragma unroll
            for (int t = 0; t < TW; ++t) {
                const int c = colg[t];
#pragma unroll
                for (int rr = 0; rr < 4; ++rr) {
                    const int row = base + q * 4 + rr;
                    if (c < DP) {
                        if constexpr (OUT_BF16)
                            ((unsigned short*)pv)[(size_t)row * DP + c] = f2b(acc[t][rr]);
                        else
                            ((float*)pv)[(size_t)row * DP + c] = acc[t][rr];
                    } else if (c < DP + DR) {
                        const float v = acc[t][rr] + bias[t];
                        if constexpr (OUT_BF16)
                            ((unsigned short*)rv)[(size_t)row * DR + (c - DP)] = f2b(v);
                        else
                            ((float*)rv)[(size_t)row * DR + (c - DP)] = v;
                    }
                }
            }
        }
    };

    const int npi = NG * NU * 16;        // nodes per block-iteration
    const int stride = gridDim.x * npi;
    int nb = blockIdx.x * npi;
    if (nb >= n) return;
    load_groups(rf0, rb0, nb);
    while (true) {
        const int nb1 = nb + stride;
        if (nb1 < n) load_groups(rf1, rb1, nb1);
        compute_groups(rf0, rb0, nb);
        nb = nb1;
        if (nb >= n) break;
        const int nb2 = nb + stride;
        if (nb2 < n) load_groups(rf0, rb0, nb2);
        compute_groups(rf1, rb1, nb);
        nb = nb2;
        if (nb >= n) break;
    }
}

// ============================ aggregation ==================================
// out[d] += mean over csr row of p rows. bf16 buffers: L=D/8 lanes per node,
// one short8 per lane per gathered row; fp32 accumulation; unroll-4 keeps
// 4 independent csr->row chains in flight.

template <int D, int L>
__global__ void agg_bf16(const int* __restrict__ rowptr,
                         const int* __restrict__ csr,
                         const unsigned short* __restrict__ p,
                         unsigned short* __restrict__ out,
                         int n) {
    constexpr int RQ = D / 8;            // short8s per row
    long long gid = (long long)blockIdx.x * blockDim.x + threadIdx.x;
    int d = (int)(gid / L);
    int l = (int)(gid % L);
    if (d >= n) return;
    int beg = rowptr[d], end = rowptr[d + 1];
    int deg = end - beg;
    if (deg <= 0) return;

    const short8* pr = reinterpret_cast<const short8*>(p);
    float s[8];
#pragma unroll
    for (int j = 0; j < 8; ++j) s[j] = 0.0f;

    int i = beg;
    for (; i + 4 <= end; i += 4) {
        int e0 = csr[i], e1 = csr[i + 1], e2 = csr[i + 2], e3 = csr[i + 3];
        short8 a = pr[(size_t)e0 * RQ + l];
        short8 b = pr[(size_t)e1 * RQ + l];
        short8 c = pr[(size_t)e2 * RQ + l];
        short8 e = pr[(size_t)e3 * RQ + l];
#pragma unroll
        for (int j = 0; j < 8; ++j)
            s[j] += (b2f((unsigned short)a[j]) + b2f((unsigned short)b[j])) +
                    (b2f((unsigned short)c[j]) + b2f((unsigned short)e[j]));
    }
    for (; i < end; ++i) {
        short8 a = pr[(size_t)csr[i] * RQ + l];
#pragma unroll
        for (int j = 0; j < 8; ++j) s[j] += b2f((unsigned short)a[j]);
    }

    const float inv = 1.0f / (float)deg;
    short8* o = reinterpret_cast<short8*>(out) + (size_t)d * RQ + l;
    short8 cur = *o;
#pragma unroll
    for (int j = 0; j < 8; ++j) {
        float v = b2f((unsigned short)cur[j]) + s[j] * inv;
        cur[j] = (short)f2b(v);
    }
    *o = cur;
}

// fp32 variant for the final layer (out = d_out, fp32)
template <int D, int L>
__global__ void agg_f32(const int* __restrict__ rowptr,
                        const int* __restrict__ csr,
                        const float* __restrict__ p,
                        float* __restrict__ out,
                        int n) {
    constexpr int RQ = D / 4;            // float4s per row
    long long gid = (long long)blockIdx.x * blockDim.x + threadIdx.x;
    int d = (int)(gid / L);
    int l = (int)(gid % L);
    if (d >= n || l >= RQ) return;
    int beg = rowptr[d], end = rowptr[d + 1];
    int deg = end - beg;
    if (deg <= 0) return;

    const float4* pr = reinterpret_cast<const float4*>(p);
    float sx = 0.f, sy = 0.f, sz = 0.f, sw = 0.f;
    int i = beg;
    for (; i + 4 <= end; i += 4) {
        int s0 = csr[i], s1 = csr[i + 1], s2 = csr[i + 2], s3 = csr[i + 3];
        float4 a = pr[(size_t)s0 * RQ + l];
        float4 b = pr[(size_t)s1 * RQ + l];
        float4 c = pr[(size_t)s2 * RQ + l];
        float4 e = pr[(size_t)s3 * RQ + l];
        sx += (a.x + b.x) + (c.x + e.x);
        sy += (a.y + b.y) + (c.y + e.y);
        sz += (a.z + b.z) + (c.z + e.z);
        sw += (a.w + b.w) + (c.w + e.w);
    }
    for (; i < end; ++i) {
        float4 a = pr[(size_t)csr[i] * RQ + l];
        sx += a.x; sy += a.y; sz += a.z; sw += a.w;
    }
    const float inv = 1.0f / (float)deg;
    float4* o = reinterpret_cast<float4*>(out) + (size_t)d * RQ + l;
    float4 cur = *o;
    cur.x += sx * inv; cur.y += sy * inv;
    cur.z += sz * inv; cur.w += sw * inv;
    *o = cur;
}

// ============================ launcher =====================================

extern "C" void kernel_launch(void* const* d_in, const int* in_sizes, int n_in,
                              void* d_out, int out_size, void* d_ws, size_t ws_size,
                              hipStream_t stream) {
    const float* x   = (const float*)d_in[0];
    const int*   ei  = (const int*)d_in[1];   // (2, E) int32
    const float* Wl1 = (const float*)d_in[2];
    const float* bl1 = (const float*)d_in[3];
    const float* Wr1 = (const float*)d_in[4];
    const float* Wl2 = (const float*)d_in[5];
    const float* bl2 = (const float*)d_in[6];
    const float* Wr2 = (const float*)d_in[7];
    const float* Wl3 = (const float*)d_in[8];
    const float* bl3 = (const float*)d_in[9];
    const float* Wr3 = (const float*)d_in[10];
    float* out = (float*)d_out;

    const int N = in_sizes[0] / 128;
    const int E = in_sizes[1] / 2;
    const int* src  = ei;
    const int* dstp = ei + E;

    // workspace (bf16 intermediates):
    //   A1 bf16 N*64 | B bf16 N*64 | A2 bf16 N*32 | C bf16 N*32 |
    //   A3 f32 N*20 | rowptr (N+1) | csr (E)
    // transient CSR ints (degi, cursor, bsum) alias A3 (dead before proj3).
    unsigned short* A1 = (unsigned short*)d_ws;
    unsigned short* Bb = A1 + (size_t)N * 64;
    unsigned short* A2 = Bb + (size_t)N * 64;
    unsigned short* Cb = A2 + (size_t)N * 32;
    float* A3 = (float*)(Cb + (size_t)N * 32);
    int* rowptr = (int*)(A3 + (size_t)N * 20);
    int* csr    = rowptr + (N + 1);

    int* degi   = (int*)A3;
    int* cursor = degi + N;
    int* bsum   = cursor + N;

    const int NB = (N + 255) / 256;  // 782 <= 1024 (scan_top limit)

    // --- CSR build ---
    zero_ints<<<NB, 256, 0, stream>>>(degi, N);
    hist_kernel<<<(E + 255) / 256, 256, 0, stream>>>(dstp, degi, E);
    scan_reduce<<<NB, 256, 0, stream>>>(degi, bsum, N);
    scan_top<<<1, 1024, 0, stream>>>(bsum, NB);
    scan_final<<<NB, 256, 0, stream>>>(degi, bsum, rowptr, cursor, N, E);
    fill_kernel<<<(E + 255) / 256, 256, 0, stream>>>(src, dstp, cursor, csr, E);

    // --- layer 1: 128 -> 64 --- fp32 in, bf16 out; CH=2, NU=1, npi=32
    // grid 1024 = exactly 4 resident blocks/CU (LDS 34816 B), balanced
    proj_mfma<128, 64, 64, 128, 2, 1, false, false, true><<<1024, 256, 0, stream>>>(
        x, Wl1, Wr1, bl1, A1, Bb, N);
    agg_bf16<64, 8><<<(int)(((long long)N * 8 + 255) / 256), 256, 0, stream>>>(
        rowptr, csr, A1, Bb, N);

    // --- layer 2: 64 -> 32 --- bf16 in (relu), bf16 out; CH=1, NU=4, npi=256
    proj_mfma<64, 32, 32, 64, 1, 4, true, true, true><<<782, 256, 0, stream>>>(
        Bb, Wl2, Wr2, bl2, A2, Cb, N);
    agg_bf16<32, 4><<<(int)(((long long)N * 4 + 255) / 256), 256, 0, stream>>>(
        rowptr, csr, A2, Cb, N);

    // --- layer 3: 32 -> 20 --- bf16 in (relu), fp32 out (p3=A3, r -> d_out)
    proj_mfma<32, 20, 20, 48, 1, 4, true, true, false><<<782, 256, 0, stream>>>(
        Cb, Wl3, Wr3, bl3, A3, out, N);
    agg_f32<20, 8><<<(int)(((long long)N * 8 + 255) / 256), 256, 0, stream>>>(
        rowptr, csr, A3, out, N);
}

// Round 7
// 351.980 us; speedup vs baseline: 2.2571x; 1.0237x over previous
//
#include <hip/hip_runtime.h>
#include <hip/hip_bf16.h>

// ---------------------------------------------------------------------------
// GraphSAGE 3-layer encoder, fp32 in/out.
//   per layer: h_out = relu?( mean_agg(h)@Wl + b + h@Wr )
// Identity: segment_sum(h[src])@Wl == segment_sum((h@Wl)[src])
//   -> project first (MFMA bf16), aggregate small vectors via CSR gather.
// R6 -> R7:
//   * B-frag LDS reads were ~8-way bank-conflicted (9.46M conflict cycles):
//     2-D W^T layout put 8 lanes on the same bank per word-phase. Weights now
//     stored in FRAGMENT ORDER, lane-contiguous (chunk ((t*S+s)*64+lane)*16B)
//     -> each wave ds_read_b128 covers a contiguous 1KB, conflict-free floor.
//   * staging = per-thread 8-scalar-load column gather (weights tiny, 1x/block).
//   * proj1 LDS now exactly 32 KB, grid 1024 (4 blocks/CU resident).
// ---------------------------------------------------------------------------

typedef __attribute__((ext_vector_type(8))) short short8;
typedef __attribute__((ext_vector_type(4))) float f32x4;

__device__ inline unsigned short f2b(float x) {
    return __bfloat16_as_ushort(__float2bfloat16(x));
}
__device__ inline float b2f(unsigned short u) {
    return __uint_as_float(((unsigned)u) << 16);
}

// ============================ CSR construction =============================

__global__ void zero_ints(int* __restrict__ p, int n) {
    int i = blockIdx.x * blockDim.x + threadIdx.x;
    if (i < n) p[i] = 0;
}

__global__ void hist_kernel(const int* __restrict__ dst, int* __restrict__ deg, int E) {
    int i = blockIdx.x * blockDim.x + threadIdx.x;
    if (i < E) atomicAdd(&deg[dst[i]], 1);
}

__global__ void scan_reduce(const int* __restrict__ deg, int* __restrict__ bsum, int n) {
    __shared__ int s[256];
    int i = blockIdx.x * 256 + threadIdx.x;
    s[threadIdx.x] = (i < n) ? deg[i] : 0;
    __syncthreads();
    for (int off = 128; off > 0; off >>= 1) {
        if (threadIdx.x < off) s[threadIdx.x] += s[threadIdx.x + off];
        __syncthreads();
    }
    if (threadIdx.x == 0) bsum[blockIdx.x] = s[0];
}

__global__ void scan_top(int* __restrict__ bsum, int nb) {
    __shared__ int s[1024];
    int t = threadIdx.x;
    int v = (t < nb) ? bsum[t] : 0;
    s[t] = v;
    __syncthreads();
    for (int off = 1; off < 1024; off <<= 1) {
        int add = (t >= off) ? s[t - off] : 0;
        __syncthreads();
        s[t] += add;
        __syncthreads();
    }
    if (t < nb) bsum[t] = s[t] - v;  // exclusive
}

__global__ void scan_final(const int* __restrict__ deg, const int* __restrict__ bsum,
                           int* __restrict__ rowptr, int* __restrict__ cursor,
                           int n, int E) {
    __shared__ int s[256];
    int t = threadIdx.x;
    int i = blockIdx.x * 256 + t;
    int v = (i < n) ? deg[i] : 0;
    s[t] = v;
    __syncthreads();
    for (int off = 1; off < 256; off <<= 1) {
        int add = (t >= off) ? s[t - off] : 0;
        __syncthreads();
        s[t] += add;
        __syncthreads();
    }
    int excl = s[t] - v + bsum[blockIdx.x];
    if (i < n) {
        rowptr[i] = excl;
        cursor[i] = excl;
    }
    if (i == 0) rowptr[n] = E;
}

__global__ void fill_kernel(const int* __restrict__ src, const int* __restrict__ dst,
                            int* __restrict__ cursor, int* __restrict__ csr, int E) {
    int e = blockIdx.x * blockDim.x + threadIdx.x;
    if (e < E) {
        int pos = atomicAdd(&cursor[dst[e]], 1);
        csr[pos] = src[e];
    }
}

// ============================ MFMA projection ==============================
// p = x@Wl ; r = x@Wr + b in one pass. Weight cols concatenated:
// [0,DP)->p, [DP,DP+DR)->r, rest zero-pad.
// LDS holds B fragments in FRAGMENT ORDER: chunk ((t*S+s)*64+lane) holds
// W~[k0..k0+7][c] for c = t*16+(lane&15), k0 = s*32+(lane>>4)*8 -> a wave's
// ds_read_b128 is lane-contiguous (conflict-free 8-phase floor).
// Raw x double-buffered in registers across grid-stride iterations; cvt/relu
// deferred to compute phase.
// MFMA 16x16x32: A[m=lane&15][k=(lane>>4)*8+i]; D col=lane&15,
// row=(lane>>4)*4+reg (verified R3-R6).

template <int DIN, int DP, int DR, int DT2, int CH, int NU,
          bool RELU, bool IN_BF16, bool OUT_BF16>
__launch_bounds__(256, 4)
__global__ void proj_mfma(const void* __restrict__ xv,
                          const float* __restrict__ Wl,
                          const float* __restrict__ Wr,
                          const float* __restrict__ bl,
                          void* __restrict__ pv,
                          void* __restrict__ rv,
                          int n) {
    constexpr int NG = 4 / CH;           // wave node-slots per block
    constexpr int TILES = DT2 / 16;
    constexpr int TW = TILES / CH;       // col tiles per wave
    constexpr int S = DIN / 32;          // MFMA k-steps
    constexpr int NCH = TILES * S * 64;  // 16B fragment chunks

    __shared__ unsigned short sF[NCH * 8];

    const int tid = threadIdx.x;
    // stage weights as lane-ordered fragments (8 scalar col-gather loads each)
    for (int chunk = tid; chunk < NCH; chunk += 256) {
        const int lane_c = chunk & 63;
        const int rest = chunk >> 6;         // t*S + s
        const int s = rest % S;
        const int t = rest / S;
        const int c = t * 16 + (lane_c & 15);
        const int k0 = s * 32 + (lane_c >> 4) * 8;
        short8 pack;
#pragma unroll
        for (int j = 0; j < 8; ++j) {
            float w = 0.f;
            const int k = k0 + j;
            if (c < DP) w = Wl[k * DP + c];
            else if (c < DP + DR) w = Wr[k * DR + (c - DP)];
            pack[j] = (short)f2b(w);
        }
        *reinterpret_cast<short8*>(&sF[(size_t)chunk * 8]) = pack;
    }
    __syncthreads();

    const int wave = tid >> 6, lane = tid & 63;
    const int ng = wave % NG;
    const int ch = wave / NG;
    const int q = lane >> 4, ln = lane & 15;
    const int colbase = ch * (TW * 16);

    // lane's fragment base: frag (t,s) at +(t*S+s)*512 ushorts
    const unsigned short* fbase = &sF[((size_t)(ch * TW * S) * 64 + lane) * 8];

    int colg[TW];
    float bias[TW];
#pragma unroll
    for (int t = 0; t < TW; ++t) {
        colg[t] = colbase + t * 16 + ln;
        bias[t] = (colg[t] >= DP && colg[t] < DP + DR) ? bl[colg[t] - DP] : 0.0f;
    }

    // raw-x double buffers (unused dtype pair is DCE'd)
    float4 rf0[NU][2 * S], rf1[NU][2 * S];
    short8 rb0[NU][S], rb1[NU][S];

    auto load_groups = [&](float4 (&rf)[NU][2 * S], short8 (&rb)[NU][S], int nbase) {
#pragma unroll
        for (int g = 0; g < NU; ++g) {
            const int base = nbase + (ng * NU + g) * 16;
            if (base >= n) continue;  // wave-uniform
            if constexpr (IN_BF16) {
                const unsigned short* xr =
                    (const unsigned short*)xv + (size_t)(base + ln) * DIN + q * 8;
#pragma unroll
                for (int s = 0; s < S; ++s)
                    rb[g][s] = *reinterpret_cast<const short8*>(xr + s * 32);
            } else {
                const float* xr = (const float*)xv + (size_t)(base + ln) * DIN + q * 8;
#pragma unroll
                for (int s = 0; s < S; ++s) {
                    rf[g][2 * s]     = *reinterpret_cast<const float4*>(xr + s * 32);
                    rf[g][2 * s + 1] = *reinterpret_cast<const float4*>(xr + s * 32 + 4);
                }
            }
        }
    };

    auto compute_groups = [&](float4 (&rf)[NU][2 * S], short8 (&rb)[NU][S], int nbase) {
#pragma unroll
        for (int g = 0; g < NU; ++g) {
            const int base = nbase + (ng * NU + g) * 16;
            if (base >= n) continue;
            short8 af[S];
#pragma unroll
            for (int s = 0; s < S; ++s) {
                if constexpr (IN_BF16) {
                    short8 a = rb[g][s];
                    if (RELU) {
#pragma unroll
                        for (int j = 0; j < 8; ++j)
                            a[j] = ((short)a[j] < 0) ? (short)0 : a[j];
                    }
                    af[s] = a;
                } else {
                    float4 v0 = rf[g][2 * s], v1 = rf[g][2 * s + 1];
                    if (RELU) {
                        v0.x = fmaxf(v0.x, 0.0f); v0.y = fmaxf(v0.y, 0.0f);
                        v0.z = fmaxf(v0.z, 0.0f); v0.w = fmaxf(v0.w, 0.0f);
                        v1.x = fmaxf(v1.x, 0.0f); v1.y = fmaxf(v1.y, 0.0f);
                        v1.z = fmaxf(v1.z, 0.0f); v1.w = fmaxf(v1.w, 0.0f);
                    }
                    short8 a;
                    a[0] = (short)f2b(v0.x); a[1] = (short)f2b(v0.y);
                    a[2] = (short)f2b(v0.z); a[3] = (short)f2b(v0.w);
                    a[4] = (short)f2b(v1.x); a[5] = (short)f2b(v1.y);
                    a[6] = (short)f2b(v1.z); a[7] = (short)f2b(v1.w);
                    af[s] = a;
                }
            }

            f32x4 acc[TW];
#pragma unroll
            for (int t = 0; t < TW; ++t) acc[t] = (f32x4){0.f, 0.f, 0.f, 0.f};
#pragma unroll
            for (int s = 0; s < S; ++s)
#pragma unroll
                for (int t = 0; t < TW; ++t) {
                    short8 bf = *reinterpret_cast<const short8*>(
                        fbase + (size_t)(t * S + s) * 512);
                    acc[t] = __builtin_amdgcn_mfma_f32_16x16x32_bf16(
                        af[s], bf, acc[t], 0, 0, 0);
                }

#pragma unroll
            for (int t = 0; t < TW; ++t) {
                const int c = colg[t];
#pragma unroll
                for (int rr = 0; rr < 4; ++rr) {
                    const int row = base + q * 4 + rr;
                    if (c < DP) {
                        if constexpr (OUT_BF16)
                            ((unsigned short*)pv)[(size_t)row * DP + c] = f2b(acc[t][rr]);
                        else
                            ((float*)pv)[(size_t)row * DP + c] = acc[t][rr];
                    } else if (c < DP + DR) {
                        const float v = acc[t][rr] + bias[t];
                        if constexpr (OUT_BF16)
                            ((unsigned short*)rv)[(size_t)row * DR + (c - DP)] = f2b(v);
                        else
                            ((float*)rv)[(size_t)row * DR + (c - DP)] = v;
                    }
                }
            }
        }
    };

    const int npi = NG * NU * 16;        // nodes per block-iteration
    const int stride = gridDim.x * npi;
    int nb = blockIdx.x * npi;
    if (nb >= n) return;
    load_groups(rf0, rb0, nb);
    while (true) {
        const int nb1 = nb + stride;
        if (nb1 < n) load_groups(rf1, rb1, nb1);
        compute_groups(rf0, rb0, nb);
        nb = nb1;
        if (nb >= n) break;
        const int nb2 = nb + stride;
        if (nb2 < n) load_groups(rf0, rb0, nb2);
        compute_groups(rf1, rb1, nb);
        nb = nb2;
        if (nb >= n) break;
    }
}

// ============================ aggregation ==================================
// out[d] += mean over csr row of p rows. bf16 buffers: L=D/8 lanes per node,
// one short8 per lane per gathered row; fp32 accumulation; unroll-4 keeps
// 4 independent csr->row chains in flight.

template <int D, int L>
__global__ void agg_bf16(const int* __restrict__ rowptr,
                         const int* __restrict__ csr,
                         const unsigned short* __restrict__ p,
                         unsigned short* __restrict__ out,
                         int n) {
    constexpr int RQ = D / 8;            // short8s per row
    long long gid = (long long)blockIdx.x * blockDim.x + threadIdx.x;
    int d = (int)(gid / L);
    int l = (int)(gid % L);
    if (d >= n) return;
    int beg = rowptr[d], end = rowptr[d + 1];
    int deg = end - beg;
    if (deg <= 0) return;

    const short8* pr = reinterpret_cast<const short8*>(p);
    float s[8];
#pragma unroll
    for (int j = 0; j < 8; ++j) s[j] = 0.0f;

    int i = beg;
    for (; i + 4 <= end; i += 4) {
        int e0 = csr[i], e1 = csr[i + 1], e2 = csr[i + 2], e3 = csr[i + 3];
        short8 a = pr[(size_t)e0 * RQ + l];
        short8 b = pr[(size_t)e1 * RQ + l];
        short8 c = pr[(size_t)e2 * RQ + l];
        short8 e = pr[(size_t)e3 * RQ + l];
#pragma unroll
        for (int j = 0; j < 8; ++j)
            s[j] += (b2f((unsigned short)a[j]) + b2f((unsigned short)b[j])) +
                    (b2f((unsigned short)c[j]) + b2f((unsigned short)e[j]));
    }
    for (; i < end; ++i) {
        short8 a = pr[(size_t)csr[i] * RQ + l];
#pragma unroll
        for (int j = 0; j < 8; ++j) s[j] += b2f((unsigned short)a[j]);
    }

    const float inv = 1.0f / (float)deg;
    short8* o = reinterpret_cast<short8*>(out) + (size_t)d * RQ + l;
    short8 cur = *o;
#pragma unroll
    for (int j = 0; j < 8; ++j) {
        float v = b2f((unsigned short)cur[j]) + s[j] * inv;
        cur[j] = (short)f2b(v);
    }
    *o = cur;
}

// fp32 variant for the final layer (out = d_out, fp32)
template <int D, int L>
__global__ void agg_f32(const int* __restrict__ rowptr,
                        const int* __restrict__ csr,
                        const float* __restrict__ p,
                        float* __restrict__ out,
                        int n) {
    constexpr int RQ = D / 4;            // float4s per row
    long long gid = (long long)blockIdx.x * blockDim.x + threadIdx.x;
    int d = (int)(gid / L);
    int l = (int)(gid % L);
    if (d >= n || l >= RQ) return;
    int beg = rowptr[d], end = rowptr[d + 1];
    int deg = end - beg;
    if (deg <= 0) return;

    const float4* pr = reinterpret_cast<const float4*>(p);
    float sx = 0.f, sy = 0.f, sz = 0.f, sw = 0.f;
    int i = beg;
    for (; i + 4 <= end; i += 4) {
        int s0 = csr[i], s1 = csr[i + 1], s2 = csr[i + 2], s3 = csr[i + 3];
        float4 a = pr[(size_t)s0 * RQ + l];
        float4 b = pr[(size_t)s1 * RQ + l];
        float4 c = pr[(size_t)s2 * RQ + l];
        float4 e = pr[(size_t)s3 * RQ + l];
        sx += (a.x + b.x) + (c.x + e.x);
        sy += (a.y + b.y) + (c.y + e.y);
        sz += (a.z + b.z) + (c.z + e.z);
        sw += (a.w + b.w) + (c.w + e.w);
    }
    for (; i < end; ++i) {
        float4 a = pr[(size_t)csr[i] * RQ + l];
        sx += a.x; sy += a.y; sz += a.z; sw += a.w;
    }
    const float inv = 1.0f / (float)deg;
    float4* o = reinterpret_cast<float4*>(out) + (size_t)d * RQ + l;
    float4 cur = *o;
    cur.x += sx * inv; cur.y += sy * inv;
    cur.z += sz * inv; cur.w += sw * inv;
    *o = cur;
}

// ============================ launcher =====================================

extern "C" void kernel_launch(void* const* d_in, const int* in_sizes, int n_in,
                              void* d_out, int out_size, void* d_ws, size_t ws_size,
                              hipStream_t stream) {
    const float* x   = (const float*)d_in[0];
    const int*   ei  = (const int*)d_in[1];   // (2, E) int32
    const float* Wl1 = (const float*)d_in[2];
    const float* bl1 = (const float*)d_in[3];
    const float* Wr1 = (const float*)d_in[4];
    const float* Wl2 = (const float*)d_in[5];
    const float* bl2 = (const float*)d_in[6];
    const float* Wr2 = (const float*)d_in[7];
    const float* Wl3 = (const float*)d_in[8];
    const float* bl3 = (const float*)d_in[9];
    const float* Wr3 = (const float*)d_in[10];
    float* out = (float*)d_out;

    const int N = in_sizes[0] / 128;
    const int E = in_sizes[1] / 2;
    const int* src  = ei;
    const int* dstp = ei + E;

    // workspace (bf16 intermediates):
    //   A1 bf16 N*64 | B bf16 N*64 | A2 bf16 N*32 | C bf16 N*32 |
    //   A3 f32 N*20 | rowptr (N+1) | csr (E)
    // transient CSR ints (degi, cursor, bsum) alias A3 (dead before proj3).
    unsigned short* A1 = (unsigned short*)d_ws;
    unsigned short* Bb = A1 + (size_t)N * 64;
    unsigned short* A2 = Bb + (size_t)N * 64;
    unsigned short* Cb = A2 + (size_t)N * 32;
    float* A3 = (float*)(Cb + (size_t)N * 32);
    int* rowptr = (int*)(A3 + (size_t)N * 20);
    int* csr    = rowptr + (N + 1);

    int* degi   = (int*)A3;
    int* cursor = degi + N;
    int* bsum   = cursor + N;

    const int NB = (N + 255) / 256;  // 782 <= 1024 (scan_top limit)

    // --- CSR build ---
    zero_ints<<<NB, 256, 0, stream>>>(degi, N);
    hist_kernel<<<(E + 255) / 256, 256, 0, stream>>>(dstp, degi, E);
    scan_reduce<<<NB, 256, 0, stream>>>(degi, bsum, N);
    scan_top<<<1, 1024, 0, stream>>>(bsum, NB);
    scan_final<<<NB, 256, 0, stream>>>(degi, bsum, rowptr, cursor, N, E);
    fill_kernel<<<(E + 255) / 256, 256, 0, stream>>>(src, dstp, cursor, csr, E);

    // --- layer 1: 128 -> 64 --- fp32 in, bf16 out; CH=2, NU=1, npi=32
    // LDS exactly 32 KB; grid 1024 = 4 resident blocks/CU, balanced
    proj_mfma<128, 64, 64, 128, 2, 1, false, false, true><<<1024, 256, 0, stream>>>(
        x, Wl1, Wr1, bl1, A1, Bb, N);
    agg_bf16<64, 8><<<(int)(((long long)N * 8 + 255) / 256), 256, 0, stream>>>(
        rowptr, csr, A1, Bb, N);

    // --- layer 2: 64 -> 32 --- bf16 in (relu), bf16 out; CH=1, NU=4, npi=256
    proj_mfma<64, 32, 32, 64, 1, 4, true, true, true><<<782, 256, 0, stream>>>(
        Bb, Wl2, Wr2, bl2, A2, Cb, N);
    agg_bf16<32, 4><<<(int)(((long long)N * 4 + 255) / 256), 256, 0, stream>>>(
        rowptr, csr, A2, Cb, N);

    // --- layer 3: 32 -> 20 --- bf16 in (relu), fp32 out (p3=A3, r -> d_out)
    proj_mfma<32, 20, 20, 48, 1, 4, true, true, false><<<782, 256, 0, stream>>>(
        Cb, Wl3, Wr3, bl3, A3, out, N);
    agg_f32<20, 8><<<(int)(((long long)N * 8 + 255) / 256), 256, 0, stream>>>(
        rowptr, csr, A3, out, N);
}